// Round 1
// baseline (1930.837 us; speedup 1.0000x reference)
//
#include <hip/hip_runtime.h>

typedef __attribute__((ext_vector_type(8))) short bf16x8;
typedef __attribute__((ext_vector_type(4))) float f32x4;

#define MFMA(a,b,c) __builtin_amdgcn_mfma_f32_16x16x32_bf16((a),(b),(c),0,0,0)

__device__ __forceinline__ short f2bf(float f){
  union { float f; unsigned u; } v; v.f = f;
  unsigned r = v.u + 0x7FFFu + ((v.u >> 16) & 1u);
  return (short)(r >> 16);
}
__device__ __forceinline__ bf16x8 pack8(float4 x, float4 y){
  bf16x8 r;
  r[0]=f2bf(x.x); r[1]=f2bf(x.y); r[2]=f2bf(x.z); r[3]=f2bf(x.w);
  r[4]=f2bf(y.x); r[5]=f2bf(y.y); r[6]=f2bf(y.z); r[7]=f2bf(y.w);
  return r;
}
// XOR-swizzled LDS addressing (16B-chunk granularity). Consistent write/read.
__device__ __forceinline__ int swz(int row, int col, int rowShorts){
  int byte = col << 1;
  int chunk = (byte & ~15) ^ ((row & 7) << 4);
  return row * rowShorts + ((chunk | (byte & 15)) >> 1);
}
// stage a 96-row x 128-col bf16 block of WT (row stride 768) into swizzled LDS. 512 threads.
__device__ __forceinline__ void stage96(short* dst, const short* WT, int rowBase, int kBase){
  int tid = threadIdx.x;
  #pragma unroll
  for (int it=0; it<3; ++it){
    int chunk = it*512 + tid;          // 0..1535
    int row = chunk >> 4;
    int c16 = chunk & 15;
    bf16x8 v = *(const bf16x8*)&WT[(size_t)(rowBase+row)*768 + kBase + c16*8];
    *(bf16x8*)&dst[swz(row, c16*8, 128)] = v;
  }
}

// ---------------- prep kernels ----------------
__global__ void prep_w(const float* __restrict__ Wq, const float* __restrict__ Wo,
                       const float* __restrict__ Wg1, short* __restrict__ WqT,
                       short* __restrict__ WoT, short* __restrict__ WaT, short* __restrict__ WbT){
  int m = blockIdx.x / 768, j = blockIdx.x % 768;
  const float* src; short* dst;
  if (m==0){ src=Wq; dst=WqT; }
  else if (m==1){ src=Wo; dst=WoT; }
  else if (m==2){ src=Wg1; dst=WaT; }
  else { src=Wg1 + (size_t)768*768; dst=WbT; }
  for (int k = threadIdx.x; k < 768; k += 256)
    dst[(size_t)j*768 + k] = f2bf(src[(size_t)k*768 + j]);
}

__global__ void prep_kv(const float* __restrict__ ce, const float* __restrict__ Wk,
                        const float* __restrict__ bk, const float* __restrict__ Wv,
                        const float* __restrict__ bv, short* __restrict__ Kc, short* __restrict__ VT){
  __shared__ float sh[768];
  int c = blockIdx.x;
  for (int h = threadIdx.x; h < 768; h += 256) sh[h] = ce[(size_t)c*768 + h];
  __syncthreads();
  for (int j = threadIdx.x; j < 768; j += 256){
    float aK = bk[j], aV = bv[j];
    for (int h=0; h<768; ++h){ float x = sh[h]; aK += x*Wk[(size_t)h*768+j]; aV += x*Wv[(size_t)h*768+j]; }
    Kc[(size_t)c*768 + j] = f2bf(aK);
    VT[(size_t)j*64 + c] = f2bf(aV);
  }
}

__global__ void prep_misc(const float* __restrict__ Wg1, const float* __restrict__ ce,
                          float* __restrict__ wg1c, float* __restrict__ cp){
  int i = blockIdx.x*256 + threadIdx.x;   // 0..1535
  if (blockIdx.x < 3){
    int j = i; float s = 0.f;
    for (int r=0; r<768; ++r) s += Wg1[(size_t)(1536+r)*768 + j];
    wg1c[j] = s;
  } else {
    int h = i - 768; float s = 0.f;
    for (int c2=0; c2<64; ++c2) s += ce[(size_t)c2*768 + h];
    cp[h] = s * (1.f/64.f);
  }
}

__global__ void pool1(const float* __restrict__ hs, float* __restrict__ tpp){
  int b = blockIdx.x >> 5, sc = blockIdx.x & 31;
  size_t base = ((size_t)b*4096 + (size_t)sc*128)*768;
  for (int h = threadIdx.x; h < 768; h += 256){
    float s = 0.f;
    for (int s2=0; s2<128; ++s2) s += hs[base + (size_t)s2*768 + h];
    tpp[(size_t)blockIdx.x*768 + h] = s;
  }
}
__global__ void pool2(const float* __restrict__ tpp, float* __restrict__ tp){
  int b = blockIdx.x / 3, hc = blockIdx.x % 3;
  int h = hc*256 + threadIdx.x;
  float s = 0.f;
  for (int k=0; k<32; ++k) s += tpp[((size_t)b*32 + k)*768 + h];
  tp[(size_t)b*768 + h] = s * (1.f/4096.f);
}
__global__ void pool3(const float* __restrict__ tp, const float* __restrict__ cp, float* __restrict__ rel){
  int b = blockIdx.x;
  float a=0.f, n1=0.f, n2=0.f;
  for (int h = threadIdx.x; h < 768; h += 256){
    float t = tp[(size_t)b*768 + h], c = cp[h];
    a += t*c; n1 += t*t; n2 += c*c;
  }
  #pragma unroll
  for (int m=1; m<64; m<<=1){ a+=__shfl_xor(a,m); n1+=__shfl_xor(n1,m); n2+=__shfl_xor(n2,m); }
  __shared__ float r3[3][4];
  int w = threadIdx.x >> 6;
  if ((threadIdx.x & 63) == 0){ r3[0][w]=a; r3[1][w]=n1; r3[2][w]=n2; }
  __syncthreads();
  if (threadIdx.x == 0){
    float A = r3[0][0]+r3[0][1]+r3[0][2]+r3[0][3];
    float N1= r3[1][0]+r3[1][1]+r3[1][2]+r3[1][3];
    float N2= r3[2][0]+r3[2][1]+r3[2][2]+r3[2][3];
    rel[b] = A / (fmaxf(sqrtf(N1),1e-8f) * fmaxf(sqrtf(N2),1e-8f));
  }
}

// ---------------- KA: Q-proj + cross-attn + Wo. Writes ctxo (f32, aliased on out rows) + attn_avg ----------------
__global__ __launch_bounds__(512, 2) void ka(
    const float* __restrict__ hs, const short* __restrict__ WqT,
    const short* __restrict__ WoT, const short* __restrict__ Kc,
    const short* __restrict__ VT, const float* __restrict__ bq,
    const float* __restrict__ bo, float* __restrict__ outp){
  extern __shared__ short lds[];
  short* ctxC = lds;           // [64][768] bf16 swz
  short* wst  = lds + 49152;   // [96][128] bf16 swz
  short* qh   = lds + 61440;   // [64][128] bf16 swz (96 cols used)
  short* attn = lds + 69632;   // [64][64]  bf16 swz
  const int tid = threadIdx.x, lane = tid & 63, w = tid >> 6;
  const int mw = w & 3, nw = w >> 2, l15 = lane & 15, g = lane >> 4;
  const size_t t0 = (size_t)blockIdx.x * 64;
  const int arow = mw*16 + l15;

  // cache hs A-fragments (bf16) for the whole K=768, reused across all 8 heads
  bf16x8 af[24];
  #pragma unroll
  for (int kk=0; kk<24; ++kk){
    const float* p = hs + (t0+arow)*768 + kk*32 + g*8;
    af[kk] = pack8(*(const float4*)p, *(const float4*)(p+4));
  }
  float aavg[16];
  #pragma unroll
  for (int i=0; i<16; ++i) aavg[i] = 0.f;

  #pragma unroll 1
  for (int h=0; h<8; ++h){
    // ---- Q-GEMM for this head (N = 96) ----
    f32x4 acc0={0,0,0,0}, acc1={0,0,0,0}, acc2={0,0,0,0};
    #pragma unroll
    for (int kb=0; kb<6; ++kb){
      __syncthreads();
      stage96(wst, WqT, h*96, kb*128);
      __syncthreads();
      #pragma unroll
      for (int ks=0; ks<4; ++ks){
        bf16x8 a = af[kb*4+ks];
        bf16x8 b0 = *(const bf16x8*)&wst[swz(nw*48 + 0  + l15, ks*32 + g*8, 128)];
        bf16x8 b1 = *(const bf16x8*)&wst[swz(nw*48 + 16 + l15, ks*32 + g*8, 128)];
        bf16x8 b2 = *(const bf16x8*)&wst[swz(nw*48 + 32 + l15, ks*32 + g*8, 128)];
        acc0 = MFMA(a,b0,acc0); acc1 = MFMA(a,b1,acc1); acc2 = MFMA(a,b2,acc2);
      }
    }
    // Q epilogue: +bias, *1/sqrt(96), -> qh (bf16)
    #pragma unroll
    for (int r=0; r<4; ++r){
      int row = mw*16 + g*4 + r;
      int j0 = nw*48 + l15;
      qh[swz(row, j0,      128)] = f2bf((acc0[r] + bq[h*96 + j0     ]) * 0.10206207262f);
      qh[swz(row, j0 + 16, 128)] = f2bf((acc1[r] + bq[h*96 + j0 + 16]) * 0.10206207262f);
      qh[swz(row, j0 + 32, 128)] = f2bf((acc2[r] + bq[h*96 + j0 + 32]) * 0.10206207262f);
    }
    __syncthreads();
    // ---- scores + softmax (waves 0-3; M=64 split 4 ways, full C=64 per wave) ----
    if (w < 4){
      f32x4 s0={0,0,0,0}, s1={0,0,0,0}, s2={0,0,0,0}, s3={0,0,0,0};
      #pragma unroll
      for (int ks=0; ks<3; ++ks){
        bf16x8 a = *(const bf16x8*)&qh[swz(w*16 + l15, ks*32 + g*8, 128)];
        const size_t kof = (size_t)h*96 + ks*32 + g*8;
        bf16x8 b0 = *(const bf16x8*)&Kc[(size_t)( 0 + l15)*768 + kof];
        bf16x8 b1 = *(const bf16x8*)&Kc[(size_t)(16 + l15)*768 + kof];
        bf16x8 b2 = *(const bf16x8*)&Kc[(size_t)(32 + l15)*768 + kof];
        bf16x8 b3 = *(const bf16x8*)&Kc[(size_t)(48 + l15)*768 + kof];
        s0 = MFMA(a,b0,s0); s1 = MFMA(a,b1,s1); s2 = MFMA(a,b2,s2); s3 = MFMA(a,b3,s3);
      }
      #pragma unroll
      for (int r=0; r<4; ++r){
        float v0=s0[r], v1=s1[r], v2=s2[r], v3=s3[r];
        float m = fmaxf(fmaxf(v0,v1), fmaxf(v2,v3));
        m = fmaxf(m, __shfl_xor(m,1)); m = fmaxf(m, __shfl_xor(m,2));
        m = fmaxf(m, __shfl_xor(m,4)); m = fmaxf(m, __shfl_xor(m,8));
        float e0=__expf(v0-m), e1=__expf(v1-m), e2=__expf(v2-m), e3=__expf(v3-m);
        float s = e0+e1+e2+e3;
        s += __shfl_xor(s,1); s += __shfl_xor(s,2); s += __shfl_xor(s,4); s += __shfl_xor(s,8);
        float inv = 1.0f / s;
        e0*=inv; e1*=inv; e2*=inv; e3*=inv;
        int row = w*16 + g*4 + r;
        attn[swz(row,  0 + l15, 64)] = f2bf(e0);
        attn[swz(row, 16 + l15, 64)] = f2bf(e1);
        attn[swz(row, 32 + l15, 64)] = f2bf(e2);
        attn[swz(row, 48 + l15, 64)] = f2bf(e3);
        aavg[r] += e0*0.125f; aavg[4+r] += e1*0.125f; aavg[8+r] += e2*0.125f; aavg[12+r] += e3*0.125f;
      }
    }
    __syncthreads();
    // ---- PV (all 8 waves) ----
    {
      f32x4 c0={0,0,0,0}, c1={0,0,0,0}, c2={0,0,0,0};
      #pragma unroll
      for (int ks=0; ks<2; ++ks){
        bf16x8 a = *(const bf16x8*)&attn[swz(mw*16 + l15, ks*32 + g*8, 64)];
        int kof = ks*32 + g*8;
        bf16x8 b0 = *(const bf16x8*)&VT[(size_t)(h*96 + nw*48 + 0  + l15)*64 + kof];
        bf16x8 b1 = *(const bf16x8*)&VT[(size_t)(h*96 + nw*48 + 16 + l15)*64 + kof];
        bf16x8 b2 = *(const bf16x8*)&VT[(size_t)(h*96 + nw*48 + 32 + l15)*64 + kof];
        c0 = MFMA(a,b0,c0); c1 = MFMA(a,b1,c1); c2 = MFMA(a,b2,c2);
      }
      #pragma unroll
      for (int r=0; r<4; ++r){
        int row = mw*16 + g*4 + r;
        int cb = h*96 + nw*48 + l15;
        ctxC[swz(row, cb,      768)] = f2bf(c0[r]);
        ctxC[swz(row, cb + 16, 768)] = f2bf(c1[r]);
        ctxC[swz(row, cb + 32, 768)] = f2bf(c2[r]);
      }
    }
  }
  __syncthreads();
  // attn_avg out (final location)
  if (w < 4){
    #pragma unroll
    for (int nt=0; nt<4; ++nt)
      #pragma unroll
      for (int r=0; r<4; ++r)
        outp[(size_t)50331648 + (t0 + w*16 + g*4 + r)*64 + nt*16 + l15] = aavg[nt*4+r];
  }
  // ---- Wo-GEMM: ctx @ Wo + bo -> ctxo (f32, aliased on out rows) ----
  bf16x8 cf[24];
  #pragma unroll
  for (int kk=0; kk<24; ++kk)
    cf[kk] = *(const bf16x8*)&ctxC[swz(arow, kk*32 + g*8, 768)];
  #pragma unroll 1
  for (int nb=0; nb<8; ++nb){
    f32x4 acc0={0,0,0,0}, acc1={0,0,0,0}, acc2={0,0,0,0};
    #pragma unroll
    for (int kb=0; kb<6; ++kb){
      __syncthreads();
      stage96(wst, WoT, nb*96, kb*128);
      __syncthreads();
      #pragma unroll
      for (int ks=0; ks<4; ++ks){
        bf16x8 a = cf[kb*4+ks];
        bf16x8 b0 = *(const bf16x8*)&wst[swz(nw*48 + 0  + l15, ks*32 + g*8, 128)];
        bf16x8 b1 = *(const bf16x8*)&wst[swz(nw*48 + 16 + l15, ks*32 + g*8, 128)];
        bf16x8 b2 = *(const bf16x8*)&wst[swz(nw*48 + 32 + l15, ks*32 + g*8, 128)];
        acc0 = MFMA(a,b0,acc0); acc1 = MFMA(a,b1,acc1); acc2 = MFMA(a,b2,acc2);
      }
    }
    #pragma unroll
    for (int r=0; r<4; ++r){
      size_t row = t0 + mw*16 + g*4 + r;
      int j0 = nb*96 + nw*48 + l15;
      outp[row*768 + j0     ] = acc0[r] + bo[j0     ];
      outp[row*768 + j0 + 16] = acc1[r] + bo[j0 + 16];
      outp[row*768 + j0 + 32] = acc2[r] + bo[j0 + 32];
    }
  }
}

// ---------------- KB: gate MLP + residual + LayerNorm (in place over ctxo rows) ----------------
__global__ __launch_bounds__(512, 2) void kb(
    const float* __restrict__ hs, const short* __restrict__ WaT,
    const short* __restrict__ WbT, const float* __restrict__ bg1,
    const float* __restrict__ wg1c, const float* __restrict__ Wg2,
    const float* __restrict__ bg2, const float* __restrict__ rel,
    const float* __restrict__ lng, const float* __restrict__ lnb,
    float* __restrict__ outp){
  __shared__ short wst[12288];
  __shared__ float gred[2][64];
  __shared__ float gl[64];
  const int tid = threadIdx.x, lane = tid & 63, w = tid >> 6;
  const int mw = w & 3, nw = w >> 2, l15 = lane & 15, g = lane >> 4;
  const size_t t0 = (size_t)blockIdx.x * 64;
  const int arow = mw*16 + l15;
  const float relb = rel[t0 >> 12];

  bf16x8 afA[24];
  #pragma unroll
  for (int kk=0; kk<24; ++kk){
    const float* p = hs + (t0+arow)*768 + kk*32 + g*8;
    afA[kk] = pack8(*(const float4*)p, *(const float4*)(p+4));
  }
  float gp[4] = {0.f,0.f,0.f,0.f};
  #pragma unroll 1
  for (int nb=0; nb<8; ++nb){
    f32x4 acc0={0,0,0,0}, acc1={0,0,0,0}, acc2={0,0,0,0};
    // pass A: hs @ Wg1a
    #pragma unroll
    for (int kb=0; kb<6; ++kb){
      __syncthreads();
      stage96(wst, WaT, nb*96, kb*128);
      __syncthreads();
      #pragma unroll
      for (int ks=0; ks<4; ++ks){
        bf16x8 a = afA[kb*4+ks];
        bf16x8 b0 = *(const bf16x8*)&wst[swz(nw*48 + 0  + l15, ks*32 + g*8, 128)];
        bf16x8 b1 = *(const bf16x8*)&wst[swz(nw*48 + 16 + l15, ks*32 + g*8, 128)];
        bf16x8 b2 = *(const bf16x8*)&wst[swz(nw*48 + 32 + l15, ks*32 + g*8, 128)];
        acc0 = MFMA(a,b0,acc0); acc1 = MFMA(a,b1,acc1); acc2 = MFMA(a,b2,acc2);
      }
    }
    // pass B: ctxo @ Wg1b (ctxo streamed from global, cvt to bf16)
    #pragma unroll
    for (int kb=0; kb<6; ++kb){
      __syncthreads();
      stage96(wst, WbT, nb*96, kb*128);
      __syncthreads();
      #pragma unroll
      for (int ks=0; ks<4; ++ks){
        const float* p = outp + (t0+arow)*768 + kb*128 + ks*32 + g*8;
        bf16x8 a = pack8(*(const float4*)p, *(const float4*)(p+4));
        bf16x8 b0 = *(const bf16x8*)&wst[swz(nw*48 + 0  + l15, ks*32 + g*8, 128)];
        bf16x8 b1 = *(const bf16x8*)&wst[swz(nw*48 + 16 + l15, ks*32 + g*8, 128)];
        bf16x8 b2 = *(const bf16x8*)&wst[swz(nw*48 + 32 + l15, ks*32 + g*8, 128)];
        acc0 = MFMA(a,b0,acc0); acc1 = MFMA(a,b1,acc1); acc2 = MFMA(a,b2,acc2);
      }
    }
    // epilogue: bias + rel-term, relu, dot with Wg2
    #pragma unroll
    for (int r=0; r<4; ++r){
      int j0 = nb*96 + nw*48 + l15;
      float h0 = fmaxf(acc0[r] + bg1[j0     ] + relb*wg1c[j0     ], 0.f);
      float h1 = fmaxf(acc1[r] + bg1[j0 + 16] + relb*wg1c[j0 + 16], 0.f);
      float h2 = fmaxf(acc2[r] + bg1[j0 + 32] + relb*wg1c[j0 + 32], 0.f);
      gp[r] += h0*Wg2[j0] + h1*Wg2[j0+16] + h2*Wg2[j0+32];
    }
  }
  // reduce gate partials: over 16 j-lanes, then across the two n-waves via LDS
  {
    float v0=gp[0], v1=gp[1], v2=gp[2], v3=gp[3];
    #pragma unroll
    for (int m=1; m<16; m<<=1){
      v0+=__shfl_xor(v0,m); v1+=__shfl_xor(v1,m); v2+=__shfl_xor(v2,m); v3+=__shfl_xor(v3,m);
    }
    if (l15 == 0){
      gred[nw][mw*16 + g*4 + 0] = v0;
      gred[nw][mw*16 + g*4 + 1] = v1;
      gred[nw][mw*16 + g*4 + 2] = v2;
      gred[nw][mw*16 + g*4 + 3] = v3;
    }
  }
  __syncthreads();
  if (tid < 64) gl[tid] = 1.f/(1.f + __expf(-(gred[0][tid] + gred[1][tid] + bg2[0])));
  __syncthreads();
  // residual + LayerNorm, in place (f32 hs + f32 ctxo), one token per wave-iteration
  #pragma unroll 1
  for (int i=0; i<8; ++i){
    int t = w*8 + i;
    float gg = gl[t];
    size_t base = (t0 + t)*768;
    float v[12]; float sum=0.f, sq=0.f;
    #pragma unroll
    for (int k2=0; k2<12; ++k2){
      int c = lane + k2*64;
      float x = hs[base + c] + gg * outp[base + c];
      v[k2] = x; sum += x; sq += x*x;
    }
    #pragma unroll
    for (int m=1; m<64; m<<=1){ sum += __shfl_xor(sum,m); sq += __shfl_xor(sq,m); }
    float mu = sum * (1.f/768.f);
    float var = sq * (1.f/768.f) - mu*mu;
    float rs = rsqrtf(var + 1e-5f);
    #pragma unroll
    for (int k2=0; k2<12; ++k2){
      int c = lane + k2*64;
      outp[base + c] = (v[k2]-mu)*rs*lng[c] + lnb[c];
    }
  }
}

extern "C" void kernel_launch(void* const* d_in, const int* in_sizes, int n_in,
                              void* d_out, int out_size, void* d_ws, size_t ws_size,
                              hipStream_t stream) {
  (void)in_sizes; (void)n_in; (void)out_size; (void)ws_size;
  const float* hs  = (const float*)d_in[0];
  const float* ce  = (const float*)d_in[1];
  const float* Wq  = (const float*)d_in[2];
  const float* bq  = (const float*)d_in[3];
  const float* Wk  = (const float*)d_in[4];
  const float* bk  = (const float*)d_in[5];
  const float* Wv  = (const float*)d_in[6];
  const float* bv  = (const float*)d_in[7];
  const float* Wo  = (const float*)d_in[8];
  const float* bo  = (const float*)d_in[9];
  const float* Wg1 = (const float*)d_in[10];
  const float* bg1 = (const float*)d_in[11];
  const float* Wg2 = (const float*)d_in[12];
  const float* bg2 = (const float*)d_in[13];
  const float* lng = (const float*)d_in[14];
  const float* lnb = (const float*)d_in[15];
  char* ws = (char*)d_ws;
  short* WqT  = (short*)(ws + 0);
  short* WoT  = (short*)(ws + 1179648);
  short* WaT  = (short*)(ws + 2359296);
  short* WbT  = (short*)(ws + 3538944);
  short* Kc   = (short*)(ws + 4718592);
  short* VT   = (short*)(ws + 4816896);
  float* wg1c = (float*)(ws + 4915200);
  float* cp   = (float*)(ws + 4918272);
  float* tp   = (float*)(ws + 4921344);
  float* rel  = (float*)(ws + 4970496);
  float* tpp  = (float*)(ws + 4970560);
  float* outp = (float*)d_out;

  prep_w   <<<3072, 256, 0, stream>>>(Wq, Wo, Wg1, WqT, WoT, WaT, WbT);
  prep_kv  <<<64,   256, 0, stream>>>(ce, Wk, bk, Wv, bv, Kc, VT);
  prep_misc<<<6,    256, 0, stream>>>(Wg1, ce, wg1c, cp);
  pool1    <<<512,  256, 0, stream>>>(hs, tpp);
  pool2    <<<48,   256, 0, stream>>>(tpp, tp);
  pool3    <<<16,   256, 0, stream>>>(tp, cp, rel);
  hipFuncSetAttribute(reinterpret_cast<const void*>(ka),
                      hipFuncAttributeMaxDynamicSharedMemorySize, 147456);
  ka<<<1024, 512, 147456, stream>>>(hs, WqT, WoT, Kc, VT, bq, bo, outp);
  kb<<<1024, 512, 0, stream>>>(hs, WaT, WbT, bg1, wg1c, Wg2, bg2, rel, lng, lnb, outp);
}

// Round 2
// 1709.905 us; speedup vs baseline: 1.1292x; 1.1292x over previous
//
#include <hip/hip_runtime.h>

typedef __attribute__((ext_vector_type(8))) short bf16x8;
typedef __attribute__((ext_vector_type(4))) float f32x4;

#define MFMA(a,b,c) __builtin_amdgcn_mfma_f32_16x16x32_bf16((a),(b),(c),0,0,0)

__device__ __forceinline__ short f2bf(float f){
  union { float f; unsigned u; } v; v.f = f;
  unsigned r = v.u + 0x7FFFu + ((v.u >> 16) & 1u);
  return (short)(r >> 16);
}
__device__ __forceinline__ float bf2f(short s){
  union { unsigned u; float f; } v; v.u = ((unsigned)(unsigned short)s) << 16; return v.f;
}
__device__ __forceinline__ bf16x8 pack8(float4 x, float4 y){
  bf16x8 r;
  r[0]=f2bf(x.x); r[1]=f2bf(x.y); r[2]=f2bf(x.z); r[3]=f2bf(x.w);
  r[4]=f2bf(y.x); r[5]=f2bf(y.y); r[6]=f2bf(y.z); r[7]=f2bf(y.w);
  return r;
}
// XOR-swizzled LDS addressing (16B-chunk granularity), row stride 128 shorts (256B)
__device__ __forceinline__ int swz(int row, int col, int rowShorts){
  int byte = col << 1;
  int chunk = (byte & ~15) ^ ((row & 7) << 4);
  return row * rowShorts + ((chunk | (byte & 15)) >> 1);
}
// async global->LDS, 16B per lane
__device__ __forceinline__ void gload16(void* lp, const void* gp){
  __builtin_amdgcn_global_load_lds((const __attribute__((address_space(1))) unsigned*)gp,
                                   (__attribute__((address_space(3))) unsigned*)lp, 16, 0, 0);
}
// stage a 32KB (128x128 bf16) image block into LDS (512 threads)
__device__ __forceinline__ void stageW(short* buf, const short* img, int w, int lane){
  const char* gp = (const char*)img;
  char* lp = (char*)buf;
  #pragma unroll
  for (int r=0; r<4; ++r)
    gload16(lp + r*8192 + w*1024, gp + r*8192 + w*1024 + lane*16);
}
// stage a 24KB (96x128 bf16) image block
__device__ __forceinline__ void stageQ(short* buf, const short* img, int w, int lane){
  const char* gp = (const char*)img;
  char* lp = (char*)buf;
  #pragma unroll
  for (int r=0; r<3; ++r)
    gload16(lp + r*8192 + w*1024, gp + r*8192 + w*1024 + lane*16);
}

// ---------------- prep: weight images (transpose + bf16 + block/swizzle pack) ----------------
// img block layout: byte x within block: row=x>>8, storage chunk sc=(x>>4)&15,
// holds logical k = ((sc ^ (row&7))<<3) + ((x>>1)&7). Blocks: (nb*6+kt) for 128-geom,
// (head*6+kt) for Wq's 96-geom.
__global__ void prep_w(const float* __restrict__ Wq, const float* __restrict__ Wo,
                       const float* __restrict__ Wg1, short* __restrict__ WqI,
                       short* __restrict__ WoI, short* __restrict__ WaI, short* __restrict__ WbI){
  __shared__ short lt[128][136];
  int blk = blockIdx.x;            // 144 = 4 mats * 6 ktiles * 6 jtiles
  int mat = blk / 36, t = blk % 36, kt = t / 6, jt = t % 6;
  const float* src = (mat==0)? Wq : (mat==1)? Wo : (mat==2)? Wg1 : (Wg1 + (size_t)768*768);
  int tid = threadIdx.x;           // 256
  for (int it=0; it<64; ++it){
    int idx = it*256 + tid;        // 0..16383
    int kl = idx >> 7, jl = idx & 127;
    lt[jl][kl] = f2bf(src[(size_t)(kt*128+kl)*768 + jt*128 + jl]);
  }
  __syncthreads();
  for (int cc=0; cc<8; ++cc){
    int ci = cc*256 + tid;         // 0..2047
    int jl = ci >> 4, sc = ci & 15;
    int jg = jt*128 + jl;
    short* dst; size_t base; int row;
    if (mat==0){ int bh = jg / 96; row = jg % 96; dst = WqI; base = (size_t)(bh*6 + kt)*12288; }
    else { row = jl; dst = (mat==1)?WoI:(mat==2)?WaI:WbI; base = (size_t)(jt*6 + kt)*16384; }
    int kkb = ((sc ^ (row & 7)) << 3);
    bf16x8 v = *(const bf16x8*)&lt[jl][kkb];
    *(bf16x8*)&dst[base + (size_t)row*128 + sc*8] = v;
  }
}

__global__ void prep_kv(const float* __restrict__ ce, const float* __restrict__ Wk,
                        const float* __restrict__ bk, const float* __restrict__ Wv,
                        const float* __restrict__ bv, short* __restrict__ Kc, short* __restrict__ VT){
  __shared__ float sh[768];
  int c = blockIdx.x, j = threadIdx.x;   // 64 blocks x 768 threads
  sh[j] = ce[(size_t)c*768 + j];
  __syncthreads();
  float aK = bk[j], aV = bv[j];
  for (int h=0; h<768; ++h){ float x = sh[h]; aK += x*Wk[(size_t)h*768+j]; aV += x*Wv[(size_t)h*768+j]; }
  Kc[(size_t)c*768 + j] = f2bf(aK);
  VT[(size_t)j*64 + c] = f2bf(aV);
}

__global__ void prep_misc(const float* __restrict__ Wg1, const float* __restrict__ ce,
                          float* __restrict__ wg1c, float* __restrict__ cp){
  int i = blockIdx.x*256 + threadIdx.x;   // 0..1535
  if (blockIdx.x < 3){
    int j = i; float s = 0.f;
    for (int r=0; r<768; ++r) s += Wg1[(size_t)(1536+r)*768 + j];
    wg1c[j] = s;
  } else {
    int h = i - 768; float s = 0.f;
    for (int c2=0; c2<64; ++c2) s += ce[(size_t)c2*768 + h];
    cp[h] = s * (1.f/64.f);
  }
}

__global__ void pool1(const float* __restrict__ hs, float* __restrict__ tpp){
  int b = blockIdx.x >> 5, sc = blockIdx.x & 31;
  size_t base = ((size_t)b*4096 + (size_t)sc*128)*768;
  for (int h = threadIdx.x; h < 768; h += 256){
    float s = 0.f;
    for (int s2=0; s2<128; ++s2) s += hs[base + (size_t)s2*768 + h];
    tpp[(size_t)blockIdx.x*768 + h] = s;
  }
}
__global__ void pool2(const float* __restrict__ tpp, float* __restrict__ tp){
  int b = blockIdx.x / 3, hc = blockIdx.x % 3;
  int h = hc*256 + threadIdx.x;
  float s = 0.f;
  for (int k=0; k<32; ++k) s += tpp[((size_t)b*32 + k)*768 + h];
  tp[(size_t)b*768 + h] = s * (1.f/4096.f);
}
__global__ void pool3(const float* __restrict__ tp, const float* __restrict__ cp, float* __restrict__ rel){
  int b = blockIdx.x;
  float a=0.f, n1=0.f, n2=0.f;
  for (int h = threadIdx.x; h < 768; h += 256){
    float t = tp[(size_t)b*768 + h], c = cp[h];
    a += t*c; n1 += t*t; n2 += c*c;
  }
  #pragma unroll
  for (int m=1; m<64; m<<=1){ a+=__shfl_xor(a,m); n1+=__shfl_xor(n1,m); n2+=__shfl_xor(n2,m); }
  __shared__ float r3[3][4];
  int w = threadIdx.x >> 6;
  if ((threadIdx.x & 63) == 0){ r3[0][w]=a; r3[1][w]=n1; r3[2][w]=n2; }
  __syncthreads();
  if (threadIdx.x == 0){
    float A = r3[0][0]+r3[0][1]+r3[0][2]+r3[0][3];
    float N1= r3[1][0]+r3[1][1]+r3[1][2]+r3[1][3];
    float N2= r3[2][0]+r3[2][1]+r3[2][2]+r3[2][3];
    rel[b] = A / (fmaxf(sqrtf(N1),1e-8f) * fmaxf(sqrtf(N2),1e-8f));
  }
}

// ---------------- KA: Q-proj + cross-attn + Wo -> ctxo (f32 on out rows) + attn_avg ----------------
__global__ __launch_bounds__(512, 2) void ka(
    const float* __restrict__ hs, const short* __restrict__ WqI,
    const short* __restrict__ WoI, const short* __restrict__ Kc,
    const short* __restrict__ VT, const float* __restrict__ bq,
    const float* __restrict__ bo, float* __restrict__ outp){
  extern __shared__ char lds[];
  short* wst0 = (short*)lds;                 // 32KB dbuf A
  short* wst1 = (short*)(lds + 32768);       // 32KB dbuf B
  short* qh   = (short*)(lds + 65536);       // 32KB [128][128] swz (Q-head / ctx-head)
  short* attb = (short*)(lds + 98304);       // 16KB [128][64] swz
  const int tid = threadIdx.x, lane = tid & 63, w = tid >> 6;
  const int l15 = lane & 15, g = lane >> 4;
  const size_t t0 = (size_t)blockIdx.x * 128;
  const int arow = w*16 + l15;    // A-frag row
  const int drow = w*16 + g*4;    // D row base (+r)

  stageQ(wst0, WqI, w, lane);     // Q(0,0) in flight during packing

  bf16x8 af[24];
  #pragma unroll
  for (int kk=0; kk<24; ++kk){
    const float* p = hs + (t0+arow)*768 + kk*32 + g*8;
    af[kk] = pack8(*(const float4*)p, *(const float4*)(p+4));
  }
  bf16x8 cf[24];
  float aavg[16];
  #pragma unroll
  for (int i=0;i<16;++i) aavg[i]=0.f;
  __syncthreads();

  int cur = 0;
  #pragma unroll
  for (int h=0; h<8; ++h){
    // ---- Q-GEMM head h (N=96, K=768), pipelined ----
    f32x4 qa[6];
    #pragma unroll
    for (int i=0;i<6;++i) qa[i] = (f32x4){0.f,0.f,0.f,0.f};
    #pragma unroll
    for (int kb=0; kb<6; ++kb){
      short* bcur = cur ? wst1 : wst0;
      short* bnxt = cur ? wst0 : wst1;
      if (kb<5)      stageQ(bnxt, WqI + (size_t)(h*6+kb+1)*12288, w, lane);
      else if (h<7)  stageQ(bnxt, WqI + (size_t)((h+1)*6)*12288, w, lane);
      else           stageW(bnxt, WoI, w, lane);
      #pragma unroll
      for (int ks=0; ks<4; ++ks){
        bf16x8 a = af[kb*4+ks];
        #pragma unroll
        for (int nt=0; nt<6; ++nt){
          bf16x8 b = *(const bf16x8*)&bcur[swz(nt*16+l15, ks*32+g*8, 128)];
          qa[nt] = MFMA(a,b,qa[nt]);
        }
      }
      __syncthreads();
      cur ^= 1;
    }
    // Q epilogue: +bias, *1/sqrt(96) -> qh
    #pragma unroll
    for (int nt=0; nt<6; ++nt)
      #pragma unroll
      for (int r=0; r<4; ++r)
        qh[swz(drow+r, nt*16+l15, 128)] = f2bf((qa[nt][r] + bq[h*96 + nt*16 + l15]) * 0.10206207262f);
    __syncthreads();
    // ---- scores + softmax (all 8 waves, each its 16 rows) ----
    {
      f32x4 sa[4];
      #pragma unroll
      for (int i=0;i<4;++i) sa[i] = (f32x4){0.f,0.f,0.f,0.f};
      #pragma unroll
      for (int ks=0; ks<3; ++ks){
        bf16x8 a = *(const bf16x8*)&qh[swz(arow, ks*32+g*8, 128)];
        #pragma unroll
        for (int cfr=0; cfr<4; ++cfr){
          bf16x8 b = *(const bf16x8*)&Kc[(size_t)(cfr*16+l15)*768 + h*96 + ks*32 + g*8];
          sa[cfr] = MFMA(a,b,sa[cfr]);
        }
      }
      #pragma unroll
      for (int r=0; r<4; ++r){
        float v0=sa[0][r], v1=sa[1][r], v2=sa[2][r], v3=sa[3][r];
        float m = fmaxf(fmaxf(v0,v1),fmaxf(v2,v3));
        m = fmaxf(m,__shfl_xor(m,1)); m = fmaxf(m,__shfl_xor(m,2));
        m = fmaxf(m,__shfl_xor(m,4)); m = fmaxf(m,__shfl_xor(m,8));
        float e0=__expf(v0-m),e1=__expf(v1-m),e2=__expf(v2-m),e3=__expf(v3-m);
        float s=e0+e1+e2+e3;
        s+=__shfl_xor(s,1); s+=__shfl_xor(s,2); s+=__shfl_xor(s,4); s+=__shfl_xor(s,8);
        float inv = 1.f/s;
        e0*=inv; e1*=inv; e2*=inv; e3*=inv;
        attb[swz(drow+r,  0+l15, 64)] = f2bf(e0);
        attb[swz(drow+r, 16+l15, 64)] = f2bf(e1);
        attb[swz(drow+r, 32+l15, 64)] = f2bf(e2);
        attb[swz(drow+r, 48+l15, 64)] = f2bf(e3);
        aavg[0+r]+=e0*0.125f; aavg[4+r]+=e1*0.125f; aavg[8+r]+=e2*0.125f; aavg[12+r]+=e3*0.125f;
      }
    }
    __syncthreads();
    // ---- PV: attn @ V-head -> ctx-head (into qh buffer) ----
    {
      f32x4 pv[6];
      #pragma unroll
      for (int i=0;i<6;++i) pv[i] = (f32x4){0.f,0.f,0.f,0.f};
      #pragma unroll
      for (int ks=0; ks<2; ++ks){
        bf16x8 a = *(const bf16x8*)&attb[swz(arow, ks*32+g*8, 64)];
        #pragma unroll
        for (int nt=0; nt<6; ++nt){
          bf16x8 b = *(const bf16x8*)&VT[(size_t)(h*96 + nt*16 + l15)*64 + ks*32 + g*8];
          pv[nt] = MFMA(a,b,pv[nt]);
        }
      }
      #pragma unroll
      for (int nt=0; nt<6; ++nt)
        #pragma unroll
        for (int r=0; r<4; ++r)
          qh[swz(drow+r, nt*16+l15, 128)] = f2bf(pv[nt][r]);
    }
    __syncthreads();
    // ctx A-frags for Wo (accumulated over heads)
    #pragma unroll
    for (int k3=0; k3<3; ++k3)
      cf[h*3+k3] = *(const bf16x8*)&qh[swz(arow, k3*32+g*8, 128)];
  }
  // attn_avg out
  #pragma unroll
  for (int cfr=0; cfr<4; ++cfr)
    #pragma unroll
    for (int r=0; r<4; ++r)
      outp[(size_t)50331648 + (t0 + drow + r)*64 + cfr*16 + l15] = aavg[cfr*4+r];
  // ---- Wo-GEMM: ctx @ Wo + bo -> ctxo (f32 on out rows) ----
  #pragma unroll 1
  for (int nb=0; nb<6; ++nb){
    f32x4 oa[8];
    #pragma unroll
    for (int i=0;i<8;++i) oa[i] = (f32x4){0.f,0.f,0.f,0.f};
    #pragma unroll
    for (int kb=0; kb<6; ++kb){
      short* bcur = cur ? wst1 : wst0;
      short* bnxt = cur ? wst0 : wst1;
      if (kb<5)      stageW(bnxt, WoI + (size_t)(nb*6+kb+1)*16384, w, lane);
      else if (nb<5) stageW(bnxt, WoI + (size_t)((nb+1)*6)*16384, w, lane);
      #pragma unroll
      for (int ks=0; ks<4; ++ks){
        bf16x8 a = cf[kb*4+ks];
        #pragma unroll
        for (int nt=0; nt<8; ++nt){
          bf16x8 b = *(const bf16x8*)&bcur[swz(nt*16+l15, ks*32+g*8, 128)];
          oa[nt] = MFMA(a,b,oa[nt]);
        }
      }
      __syncthreads();
      cur ^= 1;
    }
    #pragma unroll
    for (int nt=0; nt<8; ++nt){
      int col = nb*128 + nt*16 + l15;
      float bb = bo[col];
      #pragma unroll
      for (int r=0; r<4; ++r)
        outp[(size_t)(t0 + drow + r)*768 + col] = oa[nt][r] + bb;
    }
  }
}

// ---------------- KB: gate MLP + residual + LayerNorm (in place, zero LN re-reads) ----------------
__global__ __launch_bounds__(512, 2) void kb(
    const float* __restrict__ hs, const short* __restrict__ WaI,
    const short* __restrict__ WbI, const float* __restrict__ bg1,
    const float* __restrict__ wg1c, const float* __restrict__ Wg2,
    const float* __restrict__ bg2, const float* __restrict__ rel,
    const float* __restrict__ lng, const float* __restrict__ lnb,
    float* __restrict__ outp){
  extern __shared__ char lds[];
  short* wst0 = (short*)lds;
  short* wst1 = (short*)(lds + 32768);
  float* gl   = (float*)(lds + 65536);   // [128]
  const int tid = threadIdx.x, lane = tid & 63, w = tid >> 6;
  const int l15 = lane & 15, g = lane >> 4;
  const size_t t0 = (size_t)blockIdx.x * 128;
  const int arow = w*16 + l15;
  const int drow = w*16 + g*4;
  const float relb = rel[t0 >> 12];

  stageW(wst0, WaI, w, lane);   // first stage in flight during packing

  bf16x8 afA[24], afB[24];
  #pragma unroll
  for (int kk=0; kk<24; ++kk){
    const float* p = hs + (t0+arow)*768 + kk*32 + g*8;
    afA[kk] = pack8(*(const float4*)p, *(const float4*)(p+4));
    const float* q = outp + (t0+arow)*768 + kk*32 + g*8;
    afB[kk] = pack8(*(const float4*)q, *(const float4*)(q+4));
  }
  float gp[4] = {0.f,0.f,0.f,0.f};
  __syncthreads();

  int cur = 0;
  #pragma unroll 1
  for (int nb=0; nb<6; ++nb){
    f32x4 acc[8];
    #pragma unroll
    for (int i=0;i<8;++i) acc[i] = (f32x4){0.f,0.f,0.f,0.f};
    #pragma unroll
    for (int pass=0; pass<2; ++pass){
      #pragma unroll
      for (int kb=0; kb<6; ++kb){
        short* bcur = cur ? wst1 : wst0;
        short* bnxt = cur ? wst0 : wst1;
        if (pass==0){
          if (kb<5) stageW(bnxt, WaI + (size_t)(nb*6+kb+1)*16384, w, lane);
          else      stageW(bnxt, WbI + (size_t)(nb*6)*16384, w, lane);
        } else {
          if (kb<5)      stageW(bnxt, WbI + (size_t)(nb*6+kb+1)*16384, w, lane);
          else if (nb<5) stageW(bnxt, WaI + (size_t)((nb+1)*6)*16384, w, lane);
        }
        #pragma unroll
        for (int ks=0; ks<4; ++ks){
          bf16x8 a = pass ? afB[kb*4+ks] : afA[kb*4+ks];
          #pragma unroll
          for (int nt=0; nt<8; ++nt){
            bf16x8 b = *(const bf16x8*)&bcur[swz(nt*16+l15, ks*32+g*8, 128)];
            acc[nt] = MFMA(a,b,acc[nt]);
          }
        }
        __syncthreads();
        cur ^= 1;
      }
    }
    // epilogue: bias + rel, relu, dot Wg2
    #pragma unroll
    for (int nt=0; nt<8; ++nt){
      int col = nb*128 + nt*16 + l15;
      float b1 = bg1[col] + relb*wg1c[col];
      float w2 = Wg2[col];
      #pragma unroll
      for (int r=0; r<4; ++r)
        gp[r] += fmaxf(acc[nt][r] + b1, 0.f) * w2;
    }
  }
  // gate: reduce over 16 col-lanes -> per-row scalar -> LDS broadcast
  #pragma unroll
  for (int m=1; m<16; m<<=1){
    gp[0]+=__shfl_xor(gp[0],m); gp[1]+=__shfl_xor(gp[1],m);
    gp[2]+=__shfl_xor(gp[2],m); gp[3]+=__shfl_xor(gp[3],m);
  }
  float bg2v = bg2[0];
  if (l15 == 0){
    #pragma unroll
    for (int r=0; r<4; ++r)
      gl[drow + r] = 1.f/(1.f + __expf(-(gp[r] + bg2v)));
  }
  __syncthreads();
  // residual + LayerNorm from cached bf16 frags (no global re-reads)
  {
    float gg = gl[arow];
    float sum = 0.f, sq = 0.f;
    #pragma unroll
    for (int kk=0; kk<24; ++kk)
      #pragma unroll
      for (int j=0; j<8; ++j){
        float x = bf2f(afA[kk][j]) + gg * bf2f(afB[kk][j]);
        sum += x; sq += x*x;
      }
    sum += __shfl_xor(sum,16); sum += __shfl_xor(sum,32);
    sq  += __shfl_xor(sq,16);  sq  += __shfl_xor(sq,32);
    float mu = sum * (1.f/768.f);
    float var = sq * (1.f/768.f) - mu*mu;
    float rs = rsqrtf(var + 1e-5f);
    size_t rb = (size_t)(t0 + arow)*768;
    #pragma unroll
    for (int kk=0; kk<24; ++kk){
      int c0 = kk*32 + g*8;
      float4 ga = *(const float4*)&lng[c0], gb = *(const float4*)&lng[c0+4];
      float4 ba = *(const float4*)&lnb[c0], bb = *(const float4*)&lnb[c0+4];
      float4 o0, o1;
      o0.x = (bf2f(afA[kk][0]) + gg*bf2f(afB[kk][0]) - mu)*rs*ga.x + ba.x;
      o0.y = (bf2f(afA[kk][1]) + gg*bf2f(afB[kk][1]) - mu)*rs*ga.y + ba.y;
      o0.z = (bf2f(afA[kk][2]) + gg*bf2f(afB[kk][2]) - mu)*rs*ga.z + ba.z;
      o0.w = (bf2f(afA[kk][3]) + gg*bf2f(afB[kk][3]) - mu)*rs*ga.w + ba.w;
      o1.x = (bf2f(afA[kk][4]) + gg*bf2f(afB[kk][4]) - mu)*rs*gb.x + bb.x;
      o1.y = (bf2f(afA[kk][5]) + gg*bf2f(afB[kk][5]) - mu)*rs*gb.y + bb.y;
      o1.z = (bf2f(afA[kk][6]) + gg*bf2f(afB[kk][6]) - mu)*rs*gb.z + bb.z;
      o1.w = (bf2f(afA[kk][7]) + gg*bf2f(afB[kk][7]) - mu)*rs*gb.w + bb.w;
      *(float4*)&outp[rb + c0]     = o0;
      *(float4*)&outp[rb + c0 + 4] = o1;
    }
  }
}

extern "C" void kernel_launch(void* const* d_in, const int* in_sizes, int n_in,
                              void* d_out, int out_size, void* d_ws, size_t ws_size,
                              hipStream_t stream) {
  (void)in_sizes; (void)n_in; (void)out_size; (void)ws_size;
  const float* hs  = (const float*)d_in[0];
  const float* ce  = (const float*)d_in[1];
  const float* Wq  = (const float*)d_in[2];
  const float* bq  = (const float*)d_in[3];
  const float* Wk  = (const float*)d_in[4];
  const float* bk  = (const float*)d_in[5];
  const float* Wv  = (const float*)d_in[6];
  const float* bv  = (const float*)d_in[7];
  const float* Wo  = (const float*)d_in[8];
  const float* bo  = (const float*)d_in[9];
  const float* Wg1 = (const float*)d_in[10];
  const float* bg1 = (const float*)d_in[11];
  const float* Wg2 = (const float*)d_in[12];
  const float* bg2 = (const float*)d_in[13];
  const float* lng = (const float*)d_in[14];
  const float* lnb = (const float*)d_in[15];
  char* ws = (char*)d_ws;
  short* WqI  = (short*)(ws + 0);        // 48 blocks * 24576B
  short* WoI  = (short*)(ws + 1179648);  // 36 blocks * 32768B
  short* WaI  = (short*)(ws + 2359296);
  short* WbI  = (short*)(ws + 3538944);
  short* Kc   = (short*)(ws + 4718592);
  short* VT   = (short*)(ws + 4816896);
  float* wg1c = (float*)(ws + 4915200);
  float* cp   = (float*)(ws + 4918272);
  float* tp   = (float*)(ws + 4921344);
  float* rel  = (float*)(ws + 4970496);
  float* tpp  = (float*)(ws + 4970752);
  float* outp = (float*)d_out;

  prep_w   <<<144, 256, 0, stream>>>(Wq, Wo, Wg1, WqI, WoI, WaI, WbI);
  prep_kv  <<<64,  768, 0, stream>>>(ce, Wk, bk, Wv, bv, Kc, VT);
  prep_misc<<<6,   256, 0, stream>>>(Wg1, ce, wg1c, cp);
  pool1    <<<512, 256, 0, stream>>>(hs, tpp);
  pool2    <<<48,  256, 0, stream>>>(tpp, tp);
  pool3    <<<16,  256, 0, stream>>>(tp, cp, rel);
  hipFuncSetAttribute(reinterpret_cast<const void*>(ka),
                      hipFuncAttributeMaxDynamicSharedMemorySize, 114688);
  hipFuncSetAttribute(reinterpret_cast<const void*>(kb),
                      hipFuncAttributeMaxDynamicSharedMemorySize, 66048);
  ka<<<512, 512, 114688, stream>>>(hs, WqI, WoI, Kc, VT, bq, bo, outp);
  kb<<<512, 512, 66048,  stream>>>(hs, WaI, WbI, bg1, wg1c, Wg2, bg2, rel, lng, lnb, outp);
}

// Round 3
// 1603.224 us; speedup vs baseline: 1.2043x; 1.0665x over previous
//
#include <hip/hip_runtime.h>

typedef __attribute__((ext_vector_type(8))) short bf16x8;
typedef __attribute__((ext_vector_type(4))) float f32x4;
typedef unsigned short u16;

#define MFMA(a,b,c) __builtin_amdgcn_mfma_f32_16x16x32_bf16((a),(b),(c),0,0,0)

__device__ __forceinline__ short f2bf(float f){
  union { float f; unsigned u; } v; v.f = f;
  unsigned r = v.u + 0x7FFFu + ((v.u >> 16) & 1u);
  return (short)(r >> 16);
}
__device__ __forceinline__ float bf2f(short s){
  union { unsigned u; float f; } v; v.u = ((unsigned)(unsigned short)s) << 16; return v.f;
}
__device__ __forceinline__ bf16x8 pack8(f32x4 x, f32x4 y){
  bf16x8 r;
  r[0]=f2bf(x[0]); r[1]=f2bf(x[1]); r[2]=f2bf(x[2]); r[3]=f2bf(x[3]);
  r[4]=f2bf(y[0]); r[5]=f2bf(y[1]); r[6]=f2bf(y[2]); r[7]=f2bf(y[3]);
  return r;
}
// XOR-swizzled LDS addressing (16B-chunk granularity)
__device__ __forceinline__ int swz(int row, int col, int rowShorts){
  int byte = col << 1;
  int chunk = (byte & ~15) ^ ((row & 7) << 4);
  return row * rowShorts + ((chunk | (byte & 15)) >> 1);
}
// async global->LDS, 16B per lane; lds ptr = wave-uniform base (HW adds lane*16)
__device__ __forceinline__ void gload16(void* lp, const void* gp){
  __builtin_amdgcn_global_load_lds((const __attribute__((address_space(1))) unsigned*)gp,
                                   (__attribute__((address_space(3))) unsigned*)lp, 16, 0, 0);
}
// stage 32KB (128x128 bf16, pre-swizzled image) into LDS (512 threads)
__device__ __forceinline__ void stageW(short* buf, const short* img, int w, int lane){
  const char* gp = (const char*)img;
  char* lp = (char*)buf;
  #pragma unroll
  for (int r=0; r<4; ++r)
    gload16(lp + r*8192 + w*1024, gp + r*8192 + w*1024 + lane*16);
}
// stage 24KB (96x128 bf16) image block
__device__ __forceinline__ void stageQ(short* buf, const short* img, int w, int lane){
  const char* gp = (const char*)img;
  char* lp = (char*)buf;
  #pragma unroll
  for (int r=0; r<3; ++r)
    gload16(lp + r*8192 + w*1024, gp + r*8192 + w*1024 + lane*16);
}
// stage [128 rows][128 cols] bf16 from d_out row-scratch (row stride 1536 shorts) with
// swizzle applied at the per-lane SOURCE address; LDS dest linear. holeoff 0=ctxo, 768=ctx.
__device__ __forceinline__ void stageCtx(short* buf, const u16* rowb, int kb2, int holeoff, int w, int lane){
  int tid = w*64 + lane;
  #pragma unroll
  for (int i=0;i<4;++i){
    int id = i*512 + tid;
    int row = id>>4, sc = id&15;
    int kc = sc ^ (row&7);
    gload16((char*)buf + i*8192 + w*1024,
            rowb + (size_t)row*1536 + holeoff + kb2*128 + kc*8);
  }
}

// ---------------- prep kernels ----------------
__global__ void prep_w(const float* __restrict__ Wq, const float* __restrict__ Wo,
                       const float* __restrict__ Wg1, short* __restrict__ WqI,
                       short* __restrict__ WoI, short* __restrict__ WaI, short* __restrict__ WbI){
  __shared__ short lt[128][136];
  int blk = blockIdx.x;            // 144 = 4 mats * 6 ktiles * 6 jtiles
  int mat = blk / 36, t = blk % 36, kt = t / 6, jt = t % 6;
  const float* src = (mat==0)? Wq : (mat==1)? Wo : (mat==2)? Wg1 : (Wg1 + (size_t)768*768);
  int tid = threadIdx.x;           // 256
  for (int it=0; it<64; ++it){
    int idx = it*256 + tid;
    int kl = idx >> 7, jl = idx & 127;
    lt[jl][kl] = f2bf(src[(size_t)(kt*128+kl)*768 + jt*128 + jl]);
  }
  __syncthreads();
  for (int cc=0; cc<8; ++cc){
    int ci = cc*256 + tid;
    int jl = ci >> 4, sc = ci & 15;
    int jg = jt*128 + jl;
    short* dst; size_t base; int row;
    if (mat==0){ int bh = jg / 96; row = jg % 96; dst = WqI; base = (size_t)(bh*6 + kt)*12288; }
    else { row = jl; dst = (mat==1)?WoI:(mat==2)?WaI:WbI; base = (size_t)(jt*6 + kt)*16384; }
    int kkb = ((sc ^ (row & 7)) << 3);
    bf16x8 v = *(const bf16x8*)&lt[jl][kkb];
    *(bf16x8*)&dst[base + (size_t)row*128 + sc*8] = v;
  }
}

__global__ void prep_kv(const float* __restrict__ ce, const float* __restrict__ Wk,
                        const float* __restrict__ bk, const float* __restrict__ Wv,
                        const float* __restrict__ bv, short* __restrict__ Kc, short* __restrict__ VT){
  __shared__ float sh[8][768];
  int c0 = blockIdx.x*8, j = threadIdx.x;   // 8 blocks x 768 threads
  #pragma unroll
  for (int c2=0; c2<8; ++c2) sh[c2][j] = ce[(size_t)(c0+c2)*768 + j];
  __syncthreads();
  float aK[8], aV[8];
  float bkj = bk[j], bvj = bv[j];
  #pragma unroll
  for (int c2=0; c2<8; ++c2){ aK[c2]=bkj; aV[c2]=bvj; }
  for (int h=0; h<768; ++h){
    float wk = Wk[(size_t)h*768+j], wv = Wv[(size_t)h*768+j];
    #pragma unroll
    for (int c2=0; c2<8; ++c2){ float x = sh[c2][h]; aK[c2] += x*wk; aV[c2] += x*wv; }
  }
  #pragma unroll
  for (int c2=0; c2<8; ++c2){
    Kc[(size_t)(c0+c2)*768 + j] = f2bf(aK[c2]);
    VT[(size_t)j*64 + c0+c2] = f2bf(aV[c2]);
  }
}

__global__ void prep_misc(const float* __restrict__ Wg1, const float* __restrict__ ce,
                          float* __restrict__ wg1c, float* __restrict__ cp){
  int i = blockIdx.x*256 + threadIdx.x;   // 0..1535
  if (blockIdx.x < 3){
    int j = i; float s = 0.f;
    for (int r=0; r<768; ++r) s += Wg1[(size_t)(1536+r)*768 + j];
    wg1c[j] = s;
  } else {
    int h = i - 768; float s = 0.f;
    for (int c2=0; c2<64; ++c2) s += ce[(size_t)c2*768 + h];
    cp[h] = s * (1.f/64.f);
  }
}

__global__ void pool1(const float* __restrict__ hs, float* __restrict__ tpp){
  int b = blockIdx.x >> 5, sc = blockIdx.x & 31;
  size_t base = ((size_t)b*4096 + (size_t)sc*128)*768;
  for (int h = threadIdx.x; h < 768; h += 256){
    float s = 0.f;
    #pragma unroll 4
    for (int s2=0; s2<128; ++s2) s += __builtin_nontemporal_load(&hs[base + (size_t)s2*768 + h]);
    tpp[(size_t)blockIdx.x*768 + h] = s;
  }
}
__global__ void pool2(const float* __restrict__ tpp, float* __restrict__ tp){
  int b = blockIdx.x / 3, hc = blockIdx.x % 3;
  int h = hc*256 + threadIdx.x;
  float s = 0.f;
  for (int k=0; k<32; ++k) s += tpp[((size_t)b*32 + k)*768 + h];
  tp[(size_t)b*768 + h] = s * (1.f/4096.f);
}
__global__ void pool3(const float* __restrict__ tp, const float* __restrict__ cp, float* __restrict__ rel){
  int b = blockIdx.x;
  float a=0.f, n1=0.f, n2=0.f;
  for (int h = threadIdx.x; h < 768; h += 256){
    float t = tp[(size_t)b*768 + h], c = cp[h];
    a += t*c; n1 += t*t; n2 += c*c;
  }
  #pragma unroll
  for (int m=1; m<64; m<<=1){ a+=__shfl_xor(a,m); n1+=__shfl_xor(n1,m); n2+=__shfl_xor(n2,m); }
  __shared__ float r3[3][4];
  int w = threadIdx.x >> 6;
  if ((threadIdx.x & 63) == 0){ r3[0][w]=a; r3[1][w]=n1; r3[2][w]=n2; }
  __syncthreads();
  if (threadIdx.x == 0){
    float A = r3[0][0]+r3[0][1]+r3[0][2]+r3[0][3];
    float N1= r3[1][0]+r3[1][1]+r3[1][2]+r3[1][3];
    float N2= r3[2][0]+r3[2][1]+r3[2][2]+r3[2][3];
    rel[b] = A / (fmaxf(sqrtf(N1),1e-8f) * fmaxf(sqrtf(N2),1e-8f));
  }
}

// ---------------- KA: Q-proj + cross-attn + Wo. ctx/ctxo as bf16 in d_out row halves ----------------
__global__ __launch_bounds__(512, 2) void ka(
    const float* __restrict__ hs, const short* __restrict__ WqI,
    const short* __restrict__ WoI, const short* __restrict__ Kc,
    const short* __restrict__ VT, const float* __restrict__ bq,
    const float* __restrict__ bo, float* __restrict__ outp){
  extern __shared__ char lds[];
  short* wst0 = (short*)lds;
  short* wst1 = (short*)(lds + 32768);
  short* qh   = (short*)(lds + 65536);       // heads-phase [128][128] swz
  short* attb = (short*)(lds + 98304);       // heads-phase [128][64] swz
  short* ab0  = (short*)(lds + 65536);       // Wo-phase A dbuf (overlay)
  short* ab1  = (short*)(lds + 98304);
  const int tid = threadIdx.x, lane = tid & 63, w = tid >> 6;
  const int l15 = lane & 15, g = lane >> 4;
  const size_t t0 = (size_t)blockIdx.x * 128;
  const int arow = w*16 + l15;
  const int drow = w*16 + g*4;
  u16* myW = (u16*)outp + t0*1536;           // row scratch: [0,768) ctxo bf16, [768,1536) ctx bf16

  stageQ(wst0, WqI, w, lane);

  bf16x8 af[24];
  #pragma unroll
  for (int kk=0; kk<24; ++kk){
    const float* p = hs + (t0+arow)*768 + kk*32 + g*8;
    f32x4 x = __builtin_nontemporal_load((const f32x4*)p);
    f32x4 y = __builtin_nontemporal_load((const f32x4*)(p+4));
    af[kk] = pack8(x, y);
  }
  float aavg[16];
  #pragma unroll
  for (int i=0;i<16;++i) aavg[i]=0.f;
  __syncthreads();

  #pragma unroll 1
  for (int h=0; h<8; ++h){
    // ---- Q-GEMM head h (N=96, K=768) ----
    f32x4 qa[6];
    #pragma unroll
    for (int i=0;i<6;++i) qa[i]=(f32x4){0.f,0.f,0.f,0.f};
    #pragma unroll
    for (int kb=0; kb<6; ++kb){
      short* bc = (kb&1)? wst1 : wst0;
      short* bn = (kb&1)? wst0 : wst1;
      if (kb<5)      stageQ(bn, WqI + (size_t)(h*6+kb+1)*12288, w, lane);
      else if (h<7)  stageQ(bn, WqI + (size_t)((h+1)*6)*12288, w, lane);
      else           stageW(bn, WoI, w, lane);
      #pragma unroll
      for (int ks=0; ks<4; ++ks){
        bf16x8 a = af[kb*4+ks];
        #pragma unroll
        for (int nt=0; nt<6; ++nt)
          qa[nt] = MFMA(a, *(const bf16x8*)&bc[swz(nt*16+l15, ks*32+g*8, 128)], qa[nt]);
      }
      __syncthreads();
    }
    #pragma unroll
    for (int nt=0; nt<6; ++nt)
      #pragma unroll
      for (int r=0; r<4; ++r)
        qh[swz(drow+r, nt*16+l15, 128)] = f2bf((qa[nt][r] + bq[h*96+nt*16+l15]) * 0.10206207262f);
    __syncthreads();
    // ---- scores + softmax ----
    {
      f32x4 sa[4];
      #pragma unroll
      for (int i=0;i<4;++i) sa[i]=(f32x4){0.f,0.f,0.f,0.f};
      #pragma unroll
      for (int ks=0; ks<3; ++ks){
        bf16x8 a = *(const bf16x8*)&qh[swz(arow, ks*32+g*8, 128)];
        #pragma unroll
        for (int cf2=0; cf2<4; ++cf2)
          sa[cf2] = MFMA(a, *(const bf16x8*)&Kc[(size_t)(cf2*16+l15)*768 + h*96 + ks*32 + g*8], sa[cf2]);
      }
      #pragma unroll
      for (int r=0; r<4; ++r){
        float v0=sa[0][r], v1=sa[1][r], v2=sa[2][r], v3=sa[3][r];
        float m = fmaxf(fmaxf(v0,v1),fmaxf(v2,v3));
        m = fmaxf(m,__shfl_xor(m,1)); m = fmaxf(m,__shfl_xor(m,2));
        m = fmaxf(m,__shfl_xor(m,4)); m = fmaxf(m,__shfl_xor(m,8));
        float e0=__expf(v0-m),e1=__expf(v1-m),e2=__expf(v2-m),e3=__expf(v3-m);
        float s=e0+e1+e2+e3;
        s+=__shfl_xor(s,1); s+=__shfl_xor(s,2); s+=__shfl_xor(s,4); s+=__shfl_xor(s,8);
        float inv = 1.f/s;
        e0*=inv; e1*=inv; e2*=inv; e3*=inv;
        attb[swz(drow+r,  0+l15, 64)] = f2bf(e0);
        attb[swz(drow+r, 16+l15, 64)] = f2bf(e1);
        attb[swz(drow+r, 32+l15, 64)] = f2bf(e2);
        attb[swz(drow+r, 48+l15, 64)] = f2bf(e3);
        aavg[0+r]+=e0*0.125f; aavg[4+r]+=e1*0.125f; aavg[8+r]+=e2*0.125f; aavg[12+r]+=e3*0.125f;
      }
    }
    __syncthreads();
    // ---- PV -> ctx bf16 to row-scratch hole [768,1536) ----
    {
      f32x4 pv[6];
      #pragma unroll
      for (int i=0;i<6;++i) pv[i]=(f32x4){0.f,0.f,0.f,0.f};
      #pragma unroll
      for (int ks=0; ks<2; ++ks){
        bf16x8 a = *(const bf16x8*)&attb[swz(arow, ks*32+g*8, 64)];
        #pragma unroll
        for (int nt=0; nt<6; ++nt)
          pv[nt] = MFMA(a, *(const bf16x8*)&VT[(size_t)(h*96 + nt*16 + l15)*64 + ks*32 + g*8], pv[nt]);
      }
      #pragma unroll
      for (int nt=0; nt<6; ++nt)
        #pragma unroll
        for (int r=0; r<4; ++r)
          myW[(size_t)(drow+r)*1536 + 768 + h*96 + nt*16 + l15] = (u16)f2bf(pv[nt][r]);
    }
    __syncthreads();
  }
  // ctx stores drained by the barrier above; prefetch first A block, write attn_avg
  stageCtx(ab0, myW, 0, 768, w, lane);
  #pragma unroll
  for (int cf2=0; cf2<4; ++cf2)
    #pragma unroll
    for (int r=0; r<4; ++r)
      __builtin_nontemporal_store(aavg[cf2*4+r],
          &outp[(size_t)50331648 + (t0 + drow + r)*64 + cf2*16 + l15]);
  __syncthreads();
  // ---- Wo-GEMM: ctx @ Wo + bo -> ctxo bf16 in row-scratch [0,768) ----
  #pragma unroll 1
  for (int nb=0; nb<6; ++nb){
    f32x4 oa[8];
    #pragma unroll
    for (int i=0;i<8;++i) oa[i]=(f32x4){0.f,0.f,0.f,0.f};
    #pragma unroll
    for (int kb=0; kb<6; ++kb){
      short* wc = (kb&1)? wst1 : wst0;
      short* wn = (kb&1)? wst0 : wst1;
      short* ac = (kb&1)? ab1 : ab0;
      short* an = (kb&1)? ab0 : ab1;
      if (!((nb==5)&&(kb==5))){
        if (kb<5) stageW(wn, WoI + (size_t)(nb*6+kb+1)*16384, w, lane);
        else      stageW(wn, WoI + (size_t)((nb+1)*6)*16384, w, lane);
        stageCtx(an, myW, (kb<5)? kb+1 : 0, 768, w, lane);
      }
      #pragma unroll
      for (int ks=0; ks<4; ++ks){
        bf16x8 a = *(const bf16x8*)&ac[swz(arow, ks*32+g*8, 128)];
        #pragma unroll
        for (int nt=0; nt<8; ++nt)
          oa[nt] = MFMA(a, *(const bf16x8*)&wc[swz(nt*16+l15, ks*32+g*8, 128)], oa[nt]);
      }
      __syncthreads();
    }
    #pragma unroll
    for (int nt=0; nt<8; ++nt){
      int col = nb*128 + nt*16 + l15;
      float bb = bo[col];
      #pragma unroll
      for (int r=0; r<4; ++r)
        myW[(size_t)(drow+r)*1536 + col] = (u16)f2bf(oa[nt][r] + bb);
    }
  }
}

// ---------------- KB: gate MLP + residual + LayerNorm ----------------
__global__ __launch_bounds__(512, 2) void kb(
    const float* __restrict__ hs, const short* __restrict__ WaI,
    const short* __restrict__ WbI, const float* __restrict__ bg1,
    const float* __restrict__ wg1c, const float* __restrict__ Wg2,
    const float* __restrict__ bg2, const float* __restrict__ rel,
    const float* __restrict__ lng, const float* __restrict__ lnb,
    float* __restrict__ outp){
  extern __shared__ char lds[];
  short* wst0 = (short*)lds;
  short* wst1 = (short*)(lds + 32768);
  short* ab0  = (short*)(lds + 65536);
  short* ab1  = (short*)(lds + 98304);
  float* gl   = (float*)(lds + 131072);      // [128]
  const int tid = threadIdx.x, lane = tid & 63, w = tid >> 6;
  const int l15 = lane & 15, g = lane >> 4;
  const size_t t0 = (size_t)blockIdx.x * 128;
  const int arow = w*16 + l15;
  const int drow = w*16 + g*4;
  const float relb = rel[t0 >> 12];
  const u16* myR = (const u16*)outp + t0*1536;   // ctxo bf16 in [0,768) of each row

  stageW(wst0, WaI, w, lane);

  bf16x8 afA[24];
  #pragma unroll
  for (int kk=0; kk<24; ++kk){
    const float* p = hs + (t0+arow)*768 + kk*32 + g*8;
    f32x4 x = __builtin_nontemporal_load((const f32x4*)p);
    f32x4 y = __builtin_nontemporal_load((const f32x4*)(p+4));
    afA[kk] = pack8(x, y);
  }
  float gp[4] = {0.f,0.f,0.f,0.f};
  __syncthreads();

  #pragma unroll 1
  for (int nb=0; nb<6; ++nb){
    f32x4 acc[8];
    #pragma unroll
    for (int i=0;i<8;++i) acc[i]=(f32x4){0.f,0.f,0.f,0.f};
    // ---- pass A: hs @ Wg1a (A from registers) ----
    #pragma unroll
    for (int kb=0; kb<6; ++kb){
      short* wc = (kb&1)? wst1 : wst0;
      short* wn = (kb&1)? wst0 : wst1;
      if (kb<5) stageW(wn, WaI + (size_t)(nb*6+kb+1)*16384, w, lane);
      else {
        stageW(wn, WbI + (size_t)(nb*6)*16384, w, lane);
        if (nb==0) stageCtx(ab0, myR, 0, 0, w, lane);   // steady state: staged at (B,5)
      }
      #pragma unroll
      for (int ks=0; ks<4; ++ks){
        bf16x8 a = afA[kb*4+ks];
        #pragma unroll
        for (int nt=0; nt<8; ++nt)
          acc[nt] = MFMA(a, *(const bf16x8*)&wc[swz(nt*16+l15, ks*32+g*8, 128)], acc[nt]);
      }
      __syncthreads();
    }
    // ---- pass B: ctxo @ Wg1b (A from LDS) ----
    #pragma unroll
    for (int kb=0; kb<6; ++kb){
      short* wc = (kb&1)? wst1 : wst0;
      short* wn = (kb&1)? wst0 : wst1;
      short* ac = (kb&1)? ab1 : ab0;
      short* an = (kb&1)? ab0 : ab1;
      if (kb<5){
        stageW(wn, WbI + (size_t)(nb*6+kb+1)*16384, w, lane);
        stageCtx(an, myR, kb+1, 0, w, lane);
      } else if (nb<5){
        stageW(wn, WaI + (size_t)((nb+1)*6)*16384, w, lane);
        stageCtx(an, myR, 0, 0, w, lane);
      }
      #pragma unroll
      for (int ks=0; ks<4; ++ks){
        bf16x8 a = *(const bf16x8*)&ac[swz(arow, ks*32+g*8, 128)];
        #pragma unroll
        for (int nt=0; nt<8; ++nt)
          acc[nt] = MFMA(a, *(const bf16x8*)&wc[swz(nt*16+l15, ks*32+g*8, 128)], acc[nt]);
      }
      __syncthreads();
    }
    // epilogue: bias + rel, relu, dot Wg2
    #pragma unroll
    for (int nt=0; nt<8; ++nt){
      int col = nb*128 + nt*16 + l15;
      float b1 = bg1[col] + relb*wg1c[col];
      float w2 = Wg2[col];
      #pragma unroll
      for (int r=0; r<4; ++r)
        gp[r] += fmaxf(acc[nt][r] + b1, 0.f) * w2;
    }
  }
  // gate reduce over 16 col-lanes -> per-row sigmoid
  #pragma unroll
  for (int m=1; m<16; m<<=1){
    gp[0]+=__shfl_xor(gp[0],m); gp[1]+=__shfl_xor(gp[1],m);
    gp[2]+=__shfl_xor(gp[2],m); gp[3]+=__shfl_xor(gp[3],m);
  }
  float bg2v = bg2[0];
  if (l15 == 0){
    #pragma unroll
    for (int r=0; r<4; ++r)
      gl[drow + r] = 1.f/(1.f + __expf(-(gp[r] + bg2v)));
  }
  __syncthreads();
  // residual + LayerNorm: hs from registers, ctxo bf16 from row-scratch
  {
    float gg = gl[arow];
    bf16x8 cv[24];
    #pragma unroll
    for (int kk=0; kk<24; ++kk)
      cv[kk] = __builtin_nontemporal_load((const bf16x8*)&myR[(size_t)arow*1536 + kk*32 + g*8]);
    float sum=0.f, sq=0.f;
    #pragma unroll
    for (int kk=0; kk<24; ++kk)
      #pragma unroll
      for (int j=0; j<8; ++j){
        float x = bf2f(afA[kk][j]) + gg * bf2f(cv[kk][j]);
        sum += x; sq += x*x;
      }
    sum += __shfl_xor(sum,16); sum += __shfl_xor(sum,32);
    sq  += __shfl_xor(sq,16);  sq  += __shfl_xor(sq,32);
    float mu = sum * (1.f/768.f);
    float var = sq * (1.f/768.f) - mu*mu;
    float rs = rsqrtf(var + 1e-5f);
    size_t rb = (size_t)(t0 + arow)*768;
    #pragma unroll
    for (int kk=0; kk<24; ++kk){
      int c0 = kk*32 + g*8;
      f32x4 ga = *(const f32x4*)&lng[c0], gb = *(const f32x4*)&lng[c0+4];
      f32x4 ba = *(const f32x4*)&lnb[c0], bb = *(const f32x4*)&lnb[c0+4];
      f32x4 o0, o1;
      #pragma unroll
      for (int j=0;j<4;++j)
        o0[j] = (bf2f(afA[kk][j]) + gg*bf2f(cv[kk][j]) - mu)*rs*ga[j] + ba[j];
      #pragma unroll
      for (int j=0;j<4;++j)
        o1[j] = (bf2f(afA[kk][4+j]) + gg*bf2f(cv[kk][4+j]) - mu)*rs*gb[j] + bb[j];
      __builtin_nontemporal_store(o0, (f32x4*)&outp[rb + c0]);
      __builtin_nontemporal_store(o1, (f32x4*)&outp[rb + c0 + 4]);
    }
  }
}

extern "C" void kernel_launch(void* const* d_in, const int* in_sizes, int n_in,
                              void* d_out, int out_size, void* d_ws, size_t ws_size,
                              hipStream_t stream) {
  (void)in_sizes; (void)n_in; (void)out_size; (void)ws_size;
  const float* hs  = (const float*)d_in[0];
  const float* ce  = (const float*)d_in[1];
  const float* Wq  = (const float*)d_in[2];
  const float* bq  = (const float*)d_in[3];
  const float* Wk  = (const float*)d_in[4];
  const float* bk  = (const float*)d_in[5];
  const float* Wv  = (const float*)d_in[6];
  const float* bv  = (const float*)d_in[7];
  const float* Wo  = (const float*)d_in[8];
  const float* bo  = (const float*)d_in[9];
  const float* Wg1 = (const float*)d_in[10];
  const float* bg1 = (const float*)d_in[11];
  const float* Wg2 = (const float*)d_in[12];
  const float* bg2 = (const float*)d_in[13];
  const float* lng = (const float*)d_in[14];
  const float* lnb = (const float*)d_in[15];
  char* ws = (char*)d_ws;
  short* WqI  = (short*)(ws + 0);
  short* WoI  = (short*)(ws + 1179648);
  short* WaI  = (short*)(ws + 2359296);
  short* WbI  = (short*)(ws + 3538944);
  short* Kc   = (short*)(ws + 4718592);
  short* VT   = (short*)(ws + 4816896);
  float* wg1c = (float*)(ws + 4915200);
  float* cp   = (float*)(ws + 4918272);
  float* tp   = (float*)(ws + 4921344);
  float* rel  = (float*)(ws + 4970496);
  float* tpp  = (float*)(ws + 4970752);
  float* outp = (float*)d_out;

  prep_w   <<<144, 256, 0, stream>>>(Wq, Wo, Wg1, WqI, WoI, WaI, WbI);
  prep_kv  <<<8,   768, 0, stream>>>(ce, Wk, bk, Wv, bv, Kc, VT);
  prep_misc<<<6,   256, 0, stream>>>(Wg1, ce, wg1c, cp);
  pool1    <<<512, 256, 0, stream>>>(hs, tpp);
  pool2    <<<48,  256, 0, stream>>>(tpp, tp);
  pool3    <<<16,  256, 0, stream>>>(tp, cp, rel);
  hipFuncSetAttribute(reinterpret_cast<const void*>(ka),
                      hipFuncAttributeMaxDynamicSharedMemorySize, 131072);
  hipFuncSetAttribute(reinterpret_cast<const void*>(kb),
                      hipFuncAttributeMaxDynamicSharedMemorySize, 131584);
  ka<<<512, 512, 131072, stream>>>(hs, WqI, WoI, Kc, VT, bq, bo, outp);
  kb<<<512, 512, 131584, stream>>>(hs, WaI, WbI, bg1, wg1c, Wg2, bg2, rel, lng, lnb, outp);
}

// Round 4
// 1572.370 us; speedup vs baseline: 1.2280x; 1.0196x over previous
//
#include <hip/hip_runtime.h>

typedef __attribute__((ext_vector_type(8))) short bf16x8;
typedef __attribute__((ext_vector_type(4))) float f32x4;
typedef unsigned short u16;

#define MFMA(a,b,c) __builtin_amdgcn_mfma_f32_16x16x32_bf16((a),(b),(c),0,0,0)

__device__ __forceinline__ short f2bf(float f){
  union { float f; unsigned u; } v; v.f = f;
  unsigned r = v.u + 0x7FFFu + ((v.u >> 16) & 1u);
  return (short)(r >> 16);
}
__device__ __forceinline__ float bf2f(short s){
  union { unsigned u; float f; } v; v.u = ((unsigned)(unsigned short)s) << 16; return v.f;
}
__device__ __forceinline__ bf16x8 pack8(f32x4 x, f32x4 y){
  bf16x8 r;
  r[0]=f2bf(x[0]); r[1]=f2bf(x[1]); r[2]=f2bf(x[2]); r[3]=f2bf(x[3]);
  r[4]=f2bf(y[0]); r[5]=f2bf(y[1]); r[6]=f2bf(y[2]); r[7]=f2bf(y[3]);
  return r;
}
// XOR-swizzled LDS addressing (16B-chunk granularity)
__device__ __forceinline__ int swz(int row, int col, int rowShorts){
  int byte = col << 1;
  int chunk = (byte & ~15) ^ ((row & 7) << 4);
  return row * rowShorts + ((chunk | (byte & 15)) >> 1);
}
// async global->LDS, 16B per lane; lds ptr = wave-uniform base (HW adds lane*16)
__device__ __forceinline__ void gload16(void* lp, const void* gp){
  __builtin_amdgcn_global_load_lds((const __attribute__((address_space(1))) unsigned*)gp,
                                   (__attribute__((address_space(3))) unsigned*)lp, 16, 0, 0);
}
// stage 32KB (128x128 bf16, pre-swizzled image) into LDS (512 threads)
__device__ __forceinline__ void stageW(short* buf, const short* img, int w, int lane){
  const char* gp = (const char*)img;
  char* lp = (char*)buf;
  #pragma unroll
  for (int r=0; r<4; ++r)
    gload16(lp + r*8192 + w*1024, gp + r*8192 + w*1024 + lane*16);
}
// stage 24KB (96x128 bf16) image block
__device__ __forceinline__ void stageQ(short* buf, const short* img, int w, int lane){
  const char* gp = (const char*)img;
  char* lp = (char*)buf;
  #pragma unroll
  for (int r=0; r<3; ++r)
    gload16(lp + r*8192 + w*1024, gp + r*8192 + w*1024 + lane*16);
}

// ---------------- prep kernels ----------------
__global__ void prep_w(const float* __restrict__ Wq, const float* __restrict__ Wo,
                       const float* __restrict__ Wg1, short* __restrict__ WqI,
                       short* __restrict__ WoI, short* __restrict__ WaI, short* __restrict__ WbI){
  __shared__ short lt[128][136];
  int blk = blockIdx.x;            // 144 = 4 mats * 6 ktiles * 6 jtiles
  int mat = blk / 36, t = blk % 36, kt = t / 6, jt = t % 6;
  const float* src = (mat==0)? Wq : (mat==1)? Wo : (mat==2)? Wg1 : (Wg1 + (size_t)768*768);
  int tid = threadIdx.x;           // 256
  for (int it=0; it<64; ++it){
    int idx = it*256 + tid;
    int kl = idx >> 7, jl = idx & 127;
    lt[jl][kl] = f2bf(src[(size_t)(kt*128+kl)*768 + jt*128 + jl]);
  }
  __syncthreads();
  for (int cc=0; cc<8; ++cc){
    int ci = cc*256 + tid;
    int jl = ci >> 4, sc = ci & 15;
    int jg = jt*128 + jl;
    short* dst; size_t base; int row;
    if (mat==0){ int bh = jg / 96; row = jg % 96; dst = WqI; base = (size_t)(bh*6 + kt)*12288; }
    else { row = jl; dst = (mat==1)?WoI:(mat==2)?WaI:WbI; base = (size_t)(jt*6 + kt)*16384; }
    int kkb = ((sc ^ (row & 7)) << 3);
    bf16x8 v = *(const bf16x8*)&lt[jl][kkb];
    *(bf16x8*)&dst[base + (size_t)row*128 + sc*8] = v;
  }
}

__global__ void prep_kv(const float* __restrict__ ce, const float* __restrict__ Wk,
                        const float* __restrict__ bk, const float* __restrict__ Wv,
                        const float* __restrict__ bv, short* __restrict__ Kc, short* __restrict__ VT){
  __shared__ float sh[8][768];
  int c0 = blockIdx.x*8, j = threadIdx.x;   // 8 blocks x 768 threads
  #pragma unroll
  for (int c2=0; c2<8; ++c2) sh[c2][j] = ce[(size_t)(c0+c2)*768 + j];
  __syncthreads();
  float aK[8], aV[8];
  float bkj = bk[j], bvj = bv[j];
  #pragma unroll
  for (int c2=0; c2<8; ++c2){ aK[c2]=bkj; aV[c2]=bvj; }
  for (int h=0; h<768; ++h){
    float wk = Wk[(size_t)h*768+j], wv = Wv[(size_t)h*768+j];
    #pragma unroll
    for (int c2=0; c2<8; ++c2){ float x = sh[c2][h]; aK[c2] += x*wk; aV[c2] += x*wv; }
  }
  #pragma unroll
  for (int c2=0; c2<8; ++c2){
    Kc[(size_t)(c0+c2)*768 + j] = f2bf(aK[c2]);
    VT[(size_t)j*64 + c0+c2] = f2bf(aV[c2]);
  }
}

__global__ void prep_misc(const float* __restrict__ Wg1, const float* __restrict__ ce,
                          float* __restrict__ wg1c, float* __restrict__ cp){
  int i = blockIdx.x*256 + threadIdx.x;   // 0..1535
  if (blockIdx.x < 3){
    int j = i; float s = 0.f;
    for (int r=0; r<768; ++r) s += Wg1[(size_t)(1536+r)*768 + j];
    wg1c[j] = s;
  } else {
    int h = i - 768; float s = 0.f;
    for (int c2=0; c2<64; ++c2) s += ce[(size_t)c2*768 + h];
    cp[h] = s * (1.f/64.f);
  }
}

__global__ void pool1(const float* __restrict__ hs, float* __restrict__ tpp){
  int b = blockIdx.x >> 5, sc = blockIdx.x & 31;
  size_t base = ((size_t)b*4096 + (size_t)sc*128)*768;
  for (int h = threadIdx.x; h < 768; h += 256){
    float s = 0.f;
    #pragma unroll 4
    for (int s2=0; s2<128; ++s2) s += __builtin_nontemporal_load(&hs[base + (size_t)s2*768 + h]);
    tpp[(size_t)blockIdx.x*768 + h] = s;
  }
}
__global__ void pool2(const float* __restrict__ tpp, float* __restrict__ tp){
  int b = blockIdx.x / 3, hc = blockIdx.x % 3;
  int h = hc*256 + threadIdx.x;
  float s = 0.f;
  for (int k=0; k<32; ++k) s += tpp[((size_t)b*32 + k)*768 + h];
  tp[(size_t)b*768 + h] = s * (1.f/4096.f);
}
__global__ void pool3(const float* __restrict__ tp, const float* __restrict__ cp, float* __restrict__ rel){
  int b = blockIdx.x;
  float a=0.f, n1=0.f, n2=0.f;
  for (int h = threadIdx.x; h < 768; h += 256){
    float t = tp[(size_t)b*768 + h], c = cp[h];
    a += t*c; n1 += t*t; n2 += c*c;
  }
  #pragma unroll
  for (int m=1; m<64; m<<=1){ a+=__shfl_xor(a,m); n1+=__shfl_xor(n1,m); n2+=__shfl_xor(n2,m); }
  __shared__ float r3[3][4];
  int w = threadIdx.x >> 6;
  if ((threadIdx.x & 63) == 0){ r3[0][w]=a; r3[1][w]=n1; r3[2][w]=n2; }
  __syncthreads();
  if (threadIdx.x == 0){
    float A = r3[0][0]+r3[0][1]+r3[0][2]+r3[0][3];
    float N1= r3[1][0]+r3[1][1]+r3[1][2]+r3[1][3];
    float N2= r3[2][0]+r3[2][1]+r3[2][2]+r3[2][3];
    rel[b] = A / (fmaxf(sqrtf(N1),1e-8f) * fmaxf(sqrtf(N2),1e-8f));
  }
}

// ---------------- KA: Q-proj + cross-attn + Wo. ctx in regs; ctxo bf16 in d_out row holes ----------------
__global__ __launch_bounds__(512, 1) void ka(
    const float* __restrict__ hs, const short* __restrict__ WqI,
    const short* __restrict__ WoI, const short* __restrict__ Kc,
    const short* __restrict__ VT, const float* __restrict__ bq,
    const float* __restrict__ bo, float* __restrict__ outp){
  extern __shared__ char lds[];
  short* wst0 = (short*)lds;                 // 32KB dbuf
  short* wst1 = (short*)(lds + 32768);       // 32KB dbuf
  short* qh   = (short*)(lds + 65536);       // 32KB [128][128] swz (Q-head / ctx-head)
  short* attb = (short*)(lds + 98304);       // 16KB [128][64] swz
  float* aavgL= (float*)(lds + 114688);      // 32KB [128][64] f32
  const int tid = threadIdx.x, lane = tid & 63, w = tid >> 6;
  const int l15 = lane & 15, g = lane >> 4;
  const size_t t0 = (size_t)blockIdx.x * 128;
  const int arow = w*16 + l15;
  const int drow = w*16 + g*4;
  u16* myW = (u16*)outp + t0*1536;           // row scratch: [0,768) ctxo bf16 per row

  stageQ(wst0, WqI, w, lane);

  bf16x8 af[24];
  #pragma unroll
  for (int kk=0; kk<24; ++kk){
    const float* p = hs + (t0+arow)*768 + kk*32 + g*8;
    f32x4 x = __builtin_nontemporal_load((const f32x4*)p);
    f32x4 y = __builtin_nontemporal_load((const f32x4*)(p+4));
    af[kk] = pack8(x, y);
  }
  bf16x8 cf[24];
  for (int i=tid; i<8192; i+=512) aavgL[i] = 0.f;
  __syncthreads();

  #pragma unroll 1
  for (int h=0; h<8; ++h){
    // ---- Q-GEMM head h (N=96, K=768), 2-phase pipelined ----
    f32x4 qa[6];
    #pragma unroll
    for (int i=0;i<6;++i) qa[i]=(f32x4){0.f,0.f,0.f,0.f};
    #pragma unroll
    for (int kb2=0; kb2<6; ++kb2){
      short* bc = (kb2&1)? wst1 : wst0;
      short* bn = (kb2&1)? wst0 : wst1;
      if (kb2<5)      stageQ(bn, WqI + (size_t)(h*6+kb2+1)*12288, w, lane);
      else if (h<7)   stageQ(bn, WqI + (size_t)((h+1)*6)*12288, w, lane);
      else            stageW(bn, WoI, w, lane);
      #pragma unroll
      for (int ks=0; ks<4; ++ks){
        bf16x8 a = af[kb2*4+ks];
        #pragma unroll
        for (int nt=0; nt<6; ++nt)
          qa[nt] = MFMA(a, *(const bf16x8*)&bc[swz(nt*16+l15, ks*32+g*8, 128)], qa[nt]);
      }
      __syncthreads();
    }
    // Q epilogue -> qh (wave-local rows; no barrier needed)
    #pragma unroll
    for (int nt=0; nt<6; ++nt)
      #pragma unroll
      for (int r=0; r<4; ++r)
        qh[swz(drow+r, nt*16+l15, 128)] = f2bf((qa[nt][r] + bq[h*96+nt*16+l15]) * 0.10206207262f);
    // ---- scores + softmax (wave-local) ----
    {
      f32x4 sa[4];
      #pragma unroll
      for (int i=0;i<4;++i) sa[i]=(f32x4){0.f,0.f,0.f,0.f};
      #pragma unroll
      for (int ks=0; ks<3; ++ks){
        bf16x8 a = *(const bf16x8*)&qh[swz(arow, ks*32+g*8, 128)];
        #pragma unroll
        for (int cf2=0; cf2<4; ++cf2)
          sa[cf2] = MFMA(a, *(const bf16x8*)&Kc[(size_t)(cf2*16+l15)*768 + h*96 + ks*32 + g*8], sa[cf2]);
      }
      #pragma unroll
      for (int r=0; r<4; ++r){
        float v0=sa[0][r], v1=sa[1][r], v2=sa[2][r], v3=sa[3][r];
        float m = fmaxf(fmaxf(v0,v1),fmaxf(v2,v3));
        m = fmaxf(m,__shfl_xor(m,1)); m = fmaxf(m,__shfl_xor(m,2));
        m = fmaxf(m,__shfl_xor(m,4)); m = fmaxf(m,__shfl_xor(m,8));
        float e0=__expf(v0-m),e1=__expf(v1-m),e2=__expf(v2-m),e3=__expf(v3-m);
        float s=e0+e1+e2+e3;
        s+=__shfl_xor(s,1); s+=__shfl_xor(s,2); s+=__shfl_xor(s,4); s+=__shfl_xor(s,8);
        float inv = 1.f/s;
        e0*=inv; e1*=inv; e2*=inv; e3*=inv;
        attb[swz(drow+r,  0+l15, 64)] = f2bf(e0);
        attb[swz(drow+r, 16+l15, 64)] = f2bf(e1);
        attb[swz(drow+r, 32+l15, 64)] = f2bf(e2);
        attb[swz(drow+r, 48+l15, 64)] = f2bf(e3);
        float* ap = &aavgL[(drow+r)*64 + l15];
        ap[0]  += e0*0.125f; ap[16] += e1*0.125f;
        ap[32] += e2*0.125f; ap[48] += e3*0.125f;
      }
    }
    // ---- PV -> ctx-head into qh (wave-local), then cache to cf regs ----
    {
      f32x4 pv[6];
      #pragma unroll
      for (int i=0;i<6;++i) pv[i]=(f32x4){0.f,0.f,0.f,0.f};
      #pragma unroll
      for (int ks=0; ks<2; ++ks){
        bf16x8 a = *(const bf16x8*)&attb[swz(arow, ks*32+g*8, 64)];
        #pragma unroll
        for (int nt=0; nt<6; ++nt)
          pv[nt] = MFMA(a, *(const bf16x8*)&VT[(size_t)(h*96 + nt*16 + l15)*64 + ks*32 + g*8], pv[nt]);
      }
      #pragma unroll
      for (int nt=0; nt<6; ++nt)
        #pragma unroll
        for (int r=0; r<4; ++r)
          qh[swz(drow+r, nt*16+l15, 128)] = f2bf(pv[nt][r]);
    }
    #pragma unroll
    for (int k3=0; k3<3; ++k3)
      cf[h*3+k3] = *(const bf16x8*)&qh[swz(arow, k3*32+g*8, 128)];
  }
  // attn_avg out
  #pragma unroll
  for (int cf2=0; cf2<4; ++cf2)
    #pragma unroll
    for (int r=0; r<4; ++r)
      __builtin_nontemporal_store(aavgL[(drow+r)*64 + cf2*16 + l15],
          &outp[(size_t)50331648 + (t0 + drow + r)*64 + cf2*16 + l15]);
  // ---- Wo-GEMM: ctx(regs) @ Wo + bo -> ctxo bf16 in row-scratch [0,768) ----
  #pragma unroll 1
  for (int nb=0; nb<6; ++nb){
    f32x4 oa[8];
    #pragma unroll
    for (int i=0;i<8;++i) oa[i]=(f32x4){0.f,0.f,0.f,0.f};
    #pragma unroll
    for (int kb2=0; kb2<6; ++kb2){
      short* bc = (kb2&1)? wst1 : wst0;
      short* bn = (kb2&1)? wst0 : wst1;
      if (kb2<5)      stageW(bn, WoI + (size_t)(nb*6+kb2+1)*16384, w, lane);
      else if (nb<5)  stageW(bn, WoI + (size_t)((nb+1)*6)*16384, w, lane);
      #pragma unroll
      for (int ks=0; ks<4; ++ks){
        bf16x8 a = cf[kb2*4+ks];
        #pragma unroll
        for (int nt=0; nt<8; ++nt)
          oa[nt] = MFMA(a, *(const bf16x8*)&bc[swz(nt*16+l15, ks*32+g*8, 128)], oa[nt]);
      }
      __syncthreads();
    }
    #pragma unroll
    for (int nt=0; nt<8; ++nt){
      int col = nb*128 + nt*16 + l15;
      float bb = bo[col];
      #pragma unroll
      for (int r=0; r<4; ++r)
        myW[(size_t)(drow+r)*1536 + col] = (u16)f2bf(oa[nt][r] + bb);
    }
  }
}

// ---------------- KB: gate MLP + residual + LayerNorm (hs & ctxo both register-resident) ----------------
__global__ __launch_bounds__(512, 1) void kb(
    const float* __restrict__ hs, const short* __restrict__ WaI,
    const short* __restrict__ WbI, const float* __restrict__ bg1,
    const float* __restrict__ wg1c, const float* __restrict__ Wg2,
    const float* __restrict__ bg2, const float* __restrict__ rel,
    const float* __restrict__ lng, const float* __restrict__ lnb,
    float* __restrict__ outp){
  extern __shared__ char lds[];
  short* wst0 = (short*)lds;
  short* wst1 = (short*)(lds + 32768);
  float* gl   = (float*)(lds + 65536);       // [128]
  const int tid = threadIdx.x, lane = tid & 63, w = tid >> 6;
  const int l15 = lane & 15, g = lane >> 4;
  const size_t t0 = (size_t)blockIdx.x * 128;
  const int arow = w*16 + l15;
  const int drow = w*16 + g*4;
  const float relb = rel[t0 >> 12];
  const u16* myR = (const u16*)outp + t0*1536;   // ctxo bf16 in [0,768) of each row

  stageW(wst0, WaI, w, lane);

  bf16x8 afA[24], cfB[24];
  #pragma unroll
  for (int kk=0; kk<24; ++kk){
    const float* p = hs + (t0+arow)*768 + kk*32 + g*8;
    f32x4 x = __builtin_nontemporal_load((const f32x4*)p);
    f32x4 y = __builtin_nontemporal_load((const f32x4*)(p+4));
    afA[kk] = pack8(x, y);
    cfB[kk] = __builtin_nontemporal_load((const bf16x8*)&myR[(size_t)arow*1536 + kk*32 + g*8]);
  }
  float gp[4] = {0.f,0.f,0.f,0.f};
  __syncthreads();

  #pragma unroll 1
  for (int nb=0; nb<6; ++nb){
    f32x4 acc[8];
    #pragma unroll
    for (int i=0;i<8;++i) acc[i]=(f32x4){0.f,0.f,0.f,0.f};
    #pragma unroll
    for (int pass=0; pass<2; ++pass){
      #pragma unroll
      for (int kb2=0; kb2<6; ++kb2){
        short* bc = (kb2&1)? wst1 : wst0;
        short* bn = (kb2&1)? wst0 : wst1;
        if (pass==0){
          if (kb2<5) stageW(bn, WaI + (size_t)(nb*6+kb2+1)*16384, w, lane);
          else       stageW(bn, WbI + (size_t)(nb*6)*16384, w, lane);
        } else {
          if (kb2<5)      stageW(bn, WbI + (size_t)(nb*6+kb2+1)*16384, w, lane);
          else if (nb<5)  stageW(bn, WaI + (size_t)((nb+1)*6)*16384, w, lane);
        }
        #pragma unroll
        for (int ks=0; ks<4; ++ks){
          bf16x8 a = pass ? cfB[kb2*4+ks] : afA[kb2*4+ks];
          #pragma unroll
          for (int nt=0; nt<8; ++nt)
            acc[nt] = MFMA(a, *(const bf16x8*)&bc[swz(nt*16+l15, ks*32+g*8, 128)], acc[nt]);
        }
        __syncthreads();
      }
    }
    // epilogue: bias + rel, relu, dot Wg2
    #pragma unroll
    for (int nt=0; nt<8; ++nt){
      int col = nb*128 + nt*16 + l15;
      float b1 = bg1[col] + relb*wg1c[col];
      float w2 = Wg2[col];
      #pragma unroll
      for (int r=0; r<4; ++r)
        gp[r] += fmaxf(acc[nt][r] + b1, 0.f) * w2;
    }
  }
  // gate reduce over 16 col-lanes -> per-row sigmoid
  #pragma unroll
  for (int m=1; m<16; m<<=1){
    gp[0]+=__shfl_xor(gp[0],m); gp[1]+=__shfl_xor(gp[1],m);
    gp[2]+=__shfl_xor(gp[2],m); gp[3]+=__shfl_xor(gp[3],m);
  }
  float bg2v = bg2[0];
  if (l15 == 0){
    #pragma unroll
    for (int r=0; r<4; ++r)
      gl[drow + r] = 1.f/(1.f + __expf(-(gp[r] + bg2v)));
  }
  __syncthreads();
  // residual + LayerNorm entirely from registers
  {
    float gg = gl[arow];
    float sum=0.f, sq=0.f;
    #pragma unroll
    for (int kk=0; kk<24; ++kk)
      #pragma unroll
      for (int j=0; j<8; ++j){
        float x = bf2f(afA[kk][j]) + gg * bf2f(cfB[kk][j]);
        sum += x; sq += x*x;
      }
    sum += __shfl_xor(sum,16); sum += __shfl_xor(sum,32);
    sq  += __shfl_xor(sq,16);  sq  += __shfl_xor(sq,32);
    float mu = sum * (1.f/768.f);
    float var = sq * (1.f/768.f) - mu*mu;
    float rs = rsqrtf(var + 1e-5f);
    size_t rb = (size_t)(t0 + arow)*768;
    #pragma unroll
    for (int kk=0; kk<24; ++kk){
      int c0 = kk*32 + g*8;
      f32x4 ga = *(const f32x4*)&lng[c0], gb = *(const f32x4*)&lng[c0+4];
      f32x4 ba = *(const f32x4*)&lnb[c0], bb = *(const f32x4*)&lnb[c0+4];
      f32x4 o0, o1;
      #pragma unroll
      for (int j=0;j<4;++j)
        o0[j] = (bf2f(afA[kk][j]) + gg*bf2f(cfB[kk][j]) - mu)*rs*ga[j] + ba[j];
      #pragma unroll
      for (int j=0;j<4;++j)
        o1[j] = (bf2f(afA[kk][4+j]) + gg*bf2f(cfB[kk][4+j]) - mu)*rs*gb[j] + bb[j];
      __builtin_nontemporal_store(o0, (f32x4*)&outp[rb + c0]);
      __builtin_nontemporal_store(o1, (f32x4*)&outp[rb + c0 + 4]);
    }
  }
}

extern "C" void kernel_launch(void* const* d_in, const int* in_sizes, int n_in,
                              void* d_out, int out_size, void* d_ws, size_t ws_size,
                              hipStream_t stream) {
  (void)in_sizes; (void)n_in; (void)out_size; (void)ws_size;
  const float* hs  = (const float*)d_in[0];
  const float* ce  = (const float*)d_in[1];
  const float* Wq  = (const float*)d_in[2];
  const float* bq  = (const float*)d_in[3];
  const float* Wk  = (const float*)d_in[4];
  const float* bk  = (const float*)d_in[5];
  const float* Wv  = (const float*)d_in[6];
  const float* bv  = (const float*)d_in[7];
  const float* Wo  = (const float*)d_in[8];
  const float* bo  = (const float*)d_in[9];
  const float* Wg1 = (const float*)d_in[10];
  const float* bg1 = (const float*)d_in[11];
  const float* Wg2 = (const float*)d_in[12];
  const float* bg2 = (const float*)d_in[13];
  const float* lng = (const float*)d_in[14];
  const float* lnb = (const float*)d_in[15];
  char* ws = (char*)d_ws;
  short* WqI  = (short*)(ws + 0);
  short* WoI  = (short*)(ws + 1179648);
  short* WaI  = (short*)(ws + 2359296);
  short* WbI  = (short*)(ws + 3538944);
  short* Kc   = (short*)(ws + 4718592);
  short* VT   = (short*)(ws + 4816896);
  float* wg1c = (float*)(ws + 4915200);
  float* cp   = (float*)(ws + 4918272);
  float* tp   = (float*)(ws + 4921344);
  float* rel  = (float*)(ws + 4970496);
  float* tpp  = (float*)(ws + 4970752);
  float* outp = (float*)d_out;

  prep_w   <<<144, 256, 0, stream>>>(Wq, Wo, Wg1, WqI, WoI, WaI, WbI);
  prep_kv  <<<8,   768, 0, stream>>>(ce, Wk, bk, Wv, bv, Kc, VT);
  prep_misc<<<6,   256, 0, stream>>>(Wg1, ce, wg1c, cp);
  pool1    <<<512, 256, 0, stream>>>(hs, tpp);
  pool2    <<<48,  256, 0, stream>>>(tpp, tp);
  pool3    <<<16,  256, 0, stream>>>(tp, cp, rel);
  hipFuncSetAttribute(reinterpret_cast<const void*>(ka),
                      hipFuncAttributeMaxDynamicSharedMemorySize, 147456);
  hipFuncSetAttribute(reinterpret_cast<const void*>(kb),
                      hipFuncAttributeMaxDynamicSharedMemorySize, 66048);
  ka<<<512, 512, 147456, stream>>>(hs, WqI, WoI, Kc, VT, bq, bo, outp);
  kb<<<512, 512, 66048,  stream>>>(hs, WaI, WbI, bg1, wg1c, Wg2, bg2, rel, lng, lnb, outp);
}

// Round 5
// 1557.943 us; speedup vs baseline: 1.2394x; 1.0093x over previous
//
#include <hip/hip_runtime.h>

typedef __attribute__((ext_vector_type(8))) short bf16x8;
typedef __attribute__((ext_vector_type(4))) float f32x4;
typedef unsigned short u16;

#define MFMA(a,b,c) __builtin_amdgcn_mfma_f32_16x16x32_bf16((a),(b),(c),0,0,0)

__device__ __forceinline__ short f2bf(float f){
  union { float f; unsigned u; } v; v.f = f;
  unsigned r = v.u + 0x7FFFu + ((v.u >> 16) & 1u);
  return (short)(r >> 16);
}
__device__ __forceinline__ float bf2f(short s){
  union { unsigned u; float f; } v; v.u = ((unsigned)(unsigned short)s) << 16; return v.f;
}
__device__ __forceinline__ bf16x8 pack8(f32x4 x, f32x4 y){
  bf16x8 r;
  r[0]=f2bf(x[0]); r[1]=f2bf(x[1]); r[2]=f2bf(x[2]); r[3]=f2bf(x[3]);
  r[4]=f2bf(y[0]); r[5]=f2bf(y[1]); r[6]=f2bf(y[2]); r[7]=f2bf(y[3]);
  return r;
}
// XOR-swizzled LDS addressing (16B-chunk granularity)
__device__ __forceinline__ int swz(int row, int col, int rowShorts){
  int byte = col << 1;
  int chunk = (byte & ~15) ^ ((row & 7) << 4);
  return row * rowShorts + ((chunk | (byte & 15)) >> 1);
}
// async global->LDS, 16B per lane; lds ptr = wave-uniform base (HW adds lane*16)
__device__ __forceinline__ void gload16(void* lp, const void* gp){
  __builtin_amdgcn_global_load_lds((const __attribute__((address_space(1))) unsigned*)gp,
                                   (__attribute__((address_space(3))) unsigned*)lp, 16, 0, 0);
}
// stage 32KB (128x128 bf16, pre-swizzled image) into LDS (512 threads)
__device__ __forceinline__ void stageW(short* buf, const short* img, int w, int lane){
  const char* gp = (const char*)img;
  char* lp = (char*)buf;
  #pragma unroll
  for (int r=0; r<4; ++r)
    gload16(lp + r*8192 + w*1024, gp + r*8192 + w*1024 + lane*16);
}
// stage 24KB (96x128 bf16) image block
__device__ __forceinline__ void stageQ(short* buf, const short* img, int w, int lane){
  const char* gp = (const char*)img;
  char* lp = (char*)buf;
  #pragma unroll
  for (int r=0; r<3; ++r)
    gload16(lp + r*8192 + w*1024, gp + r*8192 + w*1024 + lane*16);
}

// ---------------- prep kernels ----------------
__global__ void prep_w(const float* __restrict__ Wq, const float* __restrict__ Wo,
                       const float* __restrict__ Wg1, short* __restrict__ WqI,
                       short* __restrict__ WoI, short* __restrict__ WaI, short* __restrict__ WbI){
  __shared__ short lt[128][136];
  int blk = blockIdx.x;            // 144 = 4 mats * 6 ktiles * 6 jtiles
  int mat = blk / 36, t = blk % 36, kt = t / 6, jt = t % 6;
  const float* src = (mat==0)? Wq : (mat==1)? Wo : (mat==2)? Wg1 : (Wg1 + (size_t)768*768);
  int tid = threadIdx.x;           // 256
  for (int it=0; it<64; ++it){
    int idx = it*256 + tid;
    int kl = idx >> 7, jl = idx & 127;
    lt[jl][kl] = f2bf(src[(size_t)(kt*128+kl)*768 + jt*128 + jl]);
  }
  __syncthreads();
  for (int cc=0; cc<8; ++cc){
    int ci = cc*256 + tid;
    int jl = ci >> 4, sc = ci & 15;
    int jg = jt*128 + jl;
    short* dst; size_t base; int row;
    if (mat==0){ int bh = jg / 96; row = jg % 96; dst = WqI; base = (size_t)(bh*6 + kt)*12288; }
    else { row = jl; dst = (mat==1)?WoI:(mat==2)?WaI:WbI; base = (size_t)(jt*6 + kt)*16384; }
    int kkb = ((sc ^ (row & 7)) << 3);
    bf16x8 v = *(const bf16x8*)&lt[jl][kkb];
    *(bf16x8*)&dst[base + (size_t)row*128 + sc*8] = v;
  }
}

__global__ void prep_kv(const float* __restrict__ ce, const float* __restrict__ Wk,
                        const float* __restrict__ bk, const float* __restrict__ Wv,
                        const float* __restrict__ bv, short* __restrict__ Kc, short* __restrict__ VT){
  __shared__ float sh[8][768];
  int c0 = blockIdx.x*8, j = threadIdx.x;   // 8 blocks x 768 threads
  #pragma unroll
  for (int c2=0; c2<8; ++c2) sh[c2][j] = ce[(size_t)(c0+c2)*768 + j];
  __syncthreads();
  float aK[8], aV[8];
  float bkj = bk[j], bvj = bv[j];
  #pragma unroll
  for (int c2=0; c2<8; ++c2){ aK[c2]=bkj; aV[c2]=bvj; }
  for (int h=0; h<768; ++h){
    float wk = Wk[(size_t)h*768+j], wv = Wv[(size_t)h*768+j];
    #pragma unroll
    for (int c2=0; c2<8; ++c2){ float x = sh[c2][h]; aK[c2] += x*wk; aV[c2] += x*wv; }
  }
  #pragma unroll
  for (int c2=0; c2<8; ++c2){
    Kc[(size_t)(c0+c2)*768 + j] = f2bf(aK[c2]);
    VT[(size_t)j*64 + c0+c2] = f2bf(aV[c2]);
  }
}

__global__ void prep_misc(const float* __restrict__ Wg1, const float* __restrict__ ce,
                          float* __restrict__ wg1c, float* __restrict__ cp){
  int i = blockIdx.x*256 + threadIdx.x;   // 0..1535
  if (blockIdx.x < 3){
    int j = i; float s = 0.f;
    for (int r=0; r<768; ++r) s += Wg1[(size_t)(1536+r)*768 + j];
    wg1c[j] = s;
  } else {
    int h = i - 768; float s = 0.f;
    for (int c2=0; c2<64; ++c2) s += ce[(size_t)c2*768 + h];
    cp[h] = s * (1.f/64.f);
  }
}

__global__ void pool1(const float* __restrict__ hs, float* __restrict__ tpp){
  int b = blockIdx.x >> 5, sc = blockIdx.x & 31;
  size_t base = ((size_t)b*4096 + (size_t)sc*128)*768;
  for (int h = threadIdx.x; h < 768; h += 256){
    float s = 0.f;
    #pragma unroll 4
    for (int s2=0; s2<128; ++s2) s += __builtin_nontemporal_load(&hs[base + (size_t)s2*768 + h]);
    tpp[(size_t)blockIdx.x*768 + h] = s;
  }
}
__global__ void pool2(const float* __restrict__ tpp, float* __restrict__ tp){
  int b = blockIdx.x / 3, hc = blockIdx.x % 3;
  int h = hc*256 + threadIdx.x;
  float s = 0.f;
  for (int k=0; k<32; ++k) s += tpp[((size_t)b*32 + k)*768 + h];
  tp[(size_t)b*768 + h] = s * (1.f/4096.f);
}
__global__ void pool3(const float* __restrict__ tp, const float* __restrict__ cp, float* __restrict__ rel){
  int b = blockIdx.x;
  float a=0.f, n1=0.f, n2=0.f;
  for (int h = threadIdx.x; h < 768; h += 256){
    float t = tp[(size_t)b*768 + h], c = cp[h];
    a += t*c; n1 += t*t; n2 += c*c;
  }
  #pragma unroll
  for (int m=1; m<64; m<<=1){ a+=__shfl_xor(a,m); n1+=__shfl_xor(n1,m); n2+=__shfl_xor(n2,m); }
  __shared__ float r3[3][4];
  int w = threadIdx.x >> 6;
  if ((threadIdx.x & 63) == 0){ r3[0][w]=a; r3[1][w]=n1; r3[2][w]=n2; }
  __syncthreads();
  if (threadIdx.x == 0){
    float A = r3[0][0]+r3[0][1]+r3[0][2]+r3[0][3];
    float N1= r3[1][0]+r3[1][1]+r3[1][2]+r3[1][3];
    float N2= r3[2][0]+r3[2][1]+r3[2][2]+r3[2][3];
    rel[b] = A / (fmaxf(sqrtf(N1),1e-8f) * fmaxf(sqrtf(N2),1e-8f));
  }
}

// ---------------- KA: Q-proj + cross-attn + Wo. ctx in regs; ctxo bf16 in d_out row holes ----------------
__global__ void __launch_bounds__(512)
__attribute__((amdgpu_waves_per_eu(2, 2))) ka(
    const float* __restrict__ hs, const short* __restrict__ WqI,
    const short* __restrict__ WoI, const short* __restrict__ Kc,
    const short* __restrict__ VT, const float* __restrict__ bq,
    const float* __restrict__ bo, float* __restrict__ outp){
  extern __shared__ char lds[];
  short* wst0 = (short*)lds;                 // 32KB dbuf
  short* wst1 = (short*)(lds + 32768);       // 32KB dbuf
  short* qh   = (short*)(lds + 65536);       // 32KB [128][128] swz (Q-head / ctx-head)
  short* attb = (short*)(lds + 98304);       // 16KB [128][64] swz
  float* aavgL= (float*)(lds + 114688);      // 32KB [128][64] f32
  const int tid = threadIdx.x, lane = tid & 63, w = tid >> 6;
  const int l15 = lane & 15, g = lane >> 4;
  const size_t t0 = (size_t)blockIdx.x * 128;
  const int arow = w*16 + l15;
  const int drow = w*16 + g*4;
  u16* myW = (u16*)outp + t0*1536;           // row scratch: [0,768) ctxo bf16 per row

  stageQ(wst0, WqI, w, lane);

  bf16x8 af[24];
  #pragma unroll
  for (int kk=0; kk<24; ++kk){
    const float* p = hs + (t0+arow)*768 + kk*32 + g*8;
    f32x4 x = __builtin_nontemporal_load((const f32x4*)p);
    f32x4 y = __builtin_nontemporal_load((const f32x4*)(p+4));
    af[kk] = pack8(x, y);
  }
  bf16x8 cf[24];
  for (int i=tid; i<8192; i+=512) aavgL[i] = 0.f;
  __syncthreads();

  #pragma unroll
  for (int h=0; h<8; ++h){
    // ---- Q-GEMM head h (N=96, K=768), 2-phase pipelined ----
    f32x4 qa[6];
    #pragma unroll
    for (int i=0;i<6;++i) qa[i]=(f32x4){0.f,0.f,0.f,0.f};
    #pragma unroll
    for (int kb2=0; kb2<6; ++kb2){
      short* bc = (kb2&1)? wst1 : wst0;
      short* bn = (kb2&1)? wst0 : wst1;
      if (kb2<5)      stageQ(bn, WqI + (size_t)(h*6+kb2+1)*12288, w, lane);
      else if (h<7)   stageQ(bn, WqI + (size_t)((h+1)*6)*12288, w, lane);
      else            stageW(bn, WoI, w, lane);
      #pragma unroll
      for (int ks=0; ks<4; ++ks){
        bf16x8 a = af[kb2*4+ks];
        #pragma unroll
        for (int nt=0; nt<6; ++nt)
          qa[nt] = MFMA(a, *(const bf16x8*)&bc[swz(nt*16+l15, ks*32+g*8, 128)], qa[nt]);
      }
      __syncthreads();
    }
    // Q epilogue -> qh (wave-local rows; no barrier needed)
    #pragma unroll
    for (int nt=0; nt<6; ++nt)
      #pragma unroll
      for (int r=0; r<4; ++r)
        qh[swz(drow+r, nt*16+l15, 128)] = f2bf((qa[nt][r] + bq[h*96+nt*16+l15]) * 0.10206207262f);
    // ---- scores + softmax (wave-local) ----
    {
      f32x4 sa[4];
      #pragma unroll
      for (int i=0;i<4;++i) sa[i]=(f32x4){0.f,0.f,0.f,0.f};
      #pragma unroll
      for (int ks=0; ks<3; ++ks){
        bf16x8 a = *(const bf16x8*)&qh[swz(arow, ks*32+g*8, 128)];
        #pragma unroll
        for (int cf2=0; cf2<4; ++cf2)
          sa[cf2] = MFMA(a, *(const bf16x8*)&Kc[(size_t)(cf2*16+l15)*768 + h*96 + ks*32 + g*8], sa[cf2]);
      }
      #pragma unroll
      for (int r=0; r<4; ++r){
        float v0=sa[0][r], v1=sa[1][r], v2=sa[2][r], v3=sa[3][r];
        float m = fmaxf(fmaxf(v0,v1),fmaxf(v2,v3));
        m = fmaxf(m,__shfl_xor(m,1)); m = fmaxf(m,__shfl_xor(m,2));
        m = fmaxf(m,__shfl_xor(m,4)); m = fmaxf(m,__shfl_xor(m,8));
        float e0=__expf(v0-m),e1=__expf(v1-m),e2=__expf(v2-m),e3=__expf(v3-m);
        float s=e0+e1+e2+e3;
        s+=__shfl_xor(s,1); s+=__shfl_xor(s,2); s+=__shfl_xor(s,4); s+=__shfl_xor(s,8);
        float inv = 1.f/s;
        e0*=inv; e1*=inv; e2*=inv; e3*=inv;
        attb[swz(drow+r,  0+l15, 64)] = f2bf(e0);
        attb[swz(drow+r, 16+l15, 64)] = f2bf(e1);
        attb[swz(drow+r, 32+l15, 64)] = f2bf(e2);
        attb[swz(drow+r, 48+l15, 64)] = f2bf(e3);
        float* ap = &aavgL[(drow+r)*64 + l15];
        ap[0]  += e0*0.125f; ap[16] += e1*0.125f;
        ap[32] += e2*0.125f; ap[48] += e3*0.125f;
      }
    }
    // ---- PV -> ctx-head into qh (wave-local), then cache to cf regs ----
    {
      f32x4 pv[6];
      #pragma unroll
      for (int i=0;i<6;++i) pv[i]=(f32x4){0.f,0.f,0.f,0.f};
      #pragma unroll
      for (int ks=0; ks<2; ++ks){
        bf16x8 a = *(const bf16x8*)&attb[swz(arow, ks*32+g*8, 64)];
        #pragma unroll
        for (int nt=0; nt<6; ++nt)
          pv[nt] = MFMA(a, *(const bf16x8*)&VT[(size_t)(h*96 + nt*16 + l15)*64 + ks*32 + g*8], pv[nt]);
      }
      #pragma unroll
      for (int nt=0; nt<6; ++nt)
        #pragma unroll
        for (int r=0; r<4; ++r)
          qh[swz(drow+r, nt*16+l15, 128)] = f2bf(pv[nt][r]);
    }
    #pragma unroll
    for (int k3=0; k3<3; ++k3)
      cf[h*3+k3] = *(const bf16x8*)&qh[swz(arow, k3*32+g*8, 128)];
  }
  // attn_avg out
  #pragma unroll
  for (int cf2=0; cf2<4; ++cf2)
    #pragma unroll
    for (int r=0; r<4; ++r)
      __builtin_nontemporal_store(aavgL[(drow+r)*64 + cf2*16 + l15],
          &outp[(size_t)50331648 + (t0 + drow + r)*64 + cf2*16 + l15]);
  // ---- Wo-GEMM: ctx(regs) @ Wo + bo -> ctxo bf16 in row-scratch [0,768) ----
  #pragma unroll 1
  for (int nb=0; nb<6; ++nb){
    f32x4 oa[8];
    #pragma unroll
    for (int i=0;i<8;++i) oa[i]=(f32x4){0.f,0.f,0.f,0.f};
    #pragma unroll
    for (int kb2=0; kb2<6; ++kb2){
      short* bc = (kb2&1)? wst1 : wst0;
      short* bn = (kb2&1)? wst0 : wst1;
      if (kb2<5)      stageW(bn, WoI + (size_t)(nb*6+kb2+1)*16384, w, lane);
      else if (nb<5)  stageW(bn, WoI + (size_t)((nb+1)*6)*16384, w, lane);
      #pragma unroll
      for (int ks=0; ks<4; ++ks){
        bf16x8 a = cf[kb2*4+ks];
        #pragma unroll
        for (int nt=0; nt<8; ++nt)
          oa[nt] = MFMA(a, *(const bf16x8*)&bc[swz(nt*16+l15, ks*32+g*8, 128)], oa[nt]);
      }
      __syncthreads();
    }
    #pragma unroll
    for (int nt=0; nt<8; ++nt){
      int col = nb*128 + nt*16 + l15;
      float bb = bo[col];
      #pragma unroll
      for (int r=0; r<4; ++r)
        myW[(size_t)(drow+r)*1536 + col] = (u16)f2bf(oa[nt][r] + bb);
    }
  }
}

// ---------------- KB: gate MLP + residual + LayerNorm (hs & ctxo both register-resident) ----------------
__global__ void __launch_bounds__(512)
__attribute__((amdgpu_waves_per_eu(2, 2))) kb(
    const float* __restrict__ hs, const short* __restrict__ WaI,
    const short* __restrict__ WbI, const float* __restrict__ bg1,
    const float* __restrict__ wg1c, const float* __restrict__ Wg2,
    const float* __restrict__ bg2, const float* __restrict__ rel,
    const float* __restrict__ lng, const float* __restrict__ lnb,
    float* __restrict__ outp){
  extern __shared__ char lds[];
  short* wst0 = (short*)lds;
  short* wst1 = (short*)(lds + 32768);
  float* gl   = (float*)(lds + 65536);       // [128]
  const int tid = threadIdx.x, lane = tid & 63, w = tid >> 6;
  const int l15 = lane & 15, g = lane >> 4;
  const size_t t0 = (size_t)blockIdx.x * 128;
  const int arow = w*16 + l15;
  const int drow = w*16 + g*4;
  const float relb = rel[t0 >> 12];
  const u16* myR = (const u16*)outp + t0*1536;   // ctxo bf16 in [0,768) of each row

  stageW(wst0, WaI, w, lane);

  bf16x8 afA[24], cfB[24];
  #pragma unroll
  for (int kk=0; kk<24; ++kk){
    const float* p = hs + (t0+arow)*768 + kk*32 + g*8;
    f32x4 x = __builtin_nontemporal_load((const f32x4*)p);
    f32x4 y = __builtin_nontemporal_load((const f32x4*)(p+4));
    afA[kk] = pack8(x, y);
    cfB[kk] = __builtin_nontemporal_load((const bf16x8*)&myR[(size_t)arow*1536 + kk*32 + g*8]);
  }
  float gp[4] = {0.f,0.f,0.f,0.f};
  __syncthreads();

  #pragma unroll 1
  for (int nb=0; nb<6; ++nb){
    f32x4 acc[8];
    #pragma unroll
    for (int i=0;i<8;++i) acc[i]=(f32x4){0.f,0.f,0.f,0.f};
    #pragma unroll
    for (int pass=0; pass<2; ++pass){
      #pragma unroll
      for (int kb2=0; kb2<6; ++kb2){
        short* bc = (kb2&1)? wst1 : wst0;
        short* bn = (kb2&1)? wst0 : wst1;
        if (pass==0){
          if (kb2<5) stageW(bn, WaI + (size_t)(nb*6+kb2+1)*16384, w, lane);
          else       stageW(bn, WbI + (size_t)(nb*6)*16384, w, lane);
        } else {
          if (kb2<5)      stageW(bn, WbI + (size_t)(nb*6+kb2+1)*16384, w, lane);
          else if (nb<5)  stageW(bn, WaI + (size_t)((nb+1)*6)*16384, w, lane);
        }
        #pragma unroll
        for (int ks=0; ks<4; ++ks){
          bf16x8 a = pass ? cfB[kb2*4+ks] : afA[kb2*4+ks];
          #pragma unroll
          for (int nt=0; nt<8; ++nt)
            acc[nt] = MFMA(a, *(const bf16x8*)&bc[swz(nt*16+l15, ks*32+g*8, 128)], acc[nt]);
        }
        __syncthreads();
      }
    }
    // epilogue: bias + rel, relu, dot Wg2
    #pragma unroll
    for (int nt=0; nt<8; ++nt){
      int col = nb*128 + nt*16 + l15;
      float b1 = bg1[col] + relb*wg1c[col];
      float w2 = Wg2[col];
      #pragma unroll
      for (int r=0; r<4; ++r)
        gp[r] += fmaxf(acc[nt][r] + b1, 0.f) * w2;
    }
  }
  // gate reduce over 16 col-lanes -> per-row sigmoid
  #pragma unroll
  for (int m=1; m<16; m<<=1){
    gp[0]+=__shfl_xor(gp[0],m); gp[1]+=__shfl_xor(gp[1],m);
    gp[2]+=__shfl_xor(gp[2],m); gp[3]+=__shfl_xor(gp[3],m);
  }
  float bg2v = bg2[0];
  if (l15 == 0){
    #pragma unroll
    for (int r=0; r<4; ++r)
      gl[drow + r] = 1.f/(1.f + __expf(-(gp[r] + bg2v)));
  }
  __syncthreads();
  // residual + LayerNorm entirely from registers
  {
    float gg = gl[arow];
    float sum=0.f, sq=0.f;
    #pragma unroll
    for (int kk=0; kk<24; ++kk)
      #pragma unroll
      for (int j=0; j<8; ++j){
        float x = bf2f(afA[kk][j]) + gg * bf2f(cfB[kk][j]);
        sum += x; sq += x*x;
      }
    sum += __shfl_xor(sum,16); sum += __shfl_xor(sum,32);
    sq  += __shfl_xor(sq,16);  sq  += __shfl_xor(sq,32);
    float mu = sum * (1.f/768.f);
    float var = sq * (1.f/768.f) - mu*mu;
    float rs = rsqrtf(var + 1e-5f);
    size_t rb = (size_t)(t0 + arow)*768;
    #pragma unroll
    for (int kk=0; kk<24; ++kk){
      int c0 = kk*32 + g*8;
      f32x4 ga = *(const f32x4*)&lng[c0], gb = *(const f32x4*)&lng[c0+4];
      f32x4 ba = *(const f32x4*)&lnb[c0], bb = *(const f32x4*)&lnb[c0+4];
      f32x4 o0, o1;
      #pragma unroll
      for (int j=0;j<4;++j)
        o0[j] = (bf2f(afA[kk][j]) + gg*bf2f(cfB[kk][j]) - mu)*rs*ga[j] + ba[j];
      #pragma unroll
      for (int j=0;j<4;++j)
        o1[j] = (bf2f(afA[kk][4+j]) + gg*bf2f(cfB[kk][4+j]) - mu)*rs*gb[j] + bb[j];
      __builtin_nontemporal_store(o0, (f32x4*)&outp[rb + c0]);
      __builtin_nontemporal_store(o1, (f32x4*)&outp[rb + c0 + 4]);
    }
  }
}

extern "C" void kernel_launch(void* const* d_in, const int* in_sizes, int n_in,
                              void* d_out, int out_size, void* d_ws, size_t ws_size,
                              hipStream_t stream) {
  (void)in_sizes; (void)n_in; (void)out_size; (void)ws_size;
  const float* hs  = (const float*)d_in[0];
  const float* ce  = (const float*)d_in[1];
  const float* Wq  = (const float*)d_in[2];
  const float* bq  = (const float*)d_in[3];
  const float* Wk  = (const float*)d_in[4];
  const float* bk  = (const float*)d_in[5];
  const float* Wv  = (const float*)d_in[6];
  const float* bv  = (const float*)d_in[7];
  const float* Wo  = (const float*)d_in[8];
  const float* bo  = (const float*)d_in[9];
  const float* Wg1 = (const float*)d_in[10];
  const float* bg1 = (const float*)d_in[11];
  const float* Wg2 = (const float*)d_in[12];
  const float* bg2 = (const float*)d_in[13];
  const float* lng = (const float*)d_in[14];
  const float* lnb = (const float*)d_in[15];
  char* ws = (char*)d_ws;
  short* WqI  = (short*)(ws + 0);
  short* WoI  = (short*)(ws + 1179648);
  short* WaI  = (short*)(ws + 2359296);
  short* WbI  = (short*)(ws + 3538944);
  short* Kc   = (short*)(ws + 4718592);
  short* VT   = (short*)(ws + 4816896);
  float* wg1c = (float*)(ws + 4915200);
  float* cp   = (float*)(ws + 4918272);
  float* tp   = (float*)(ws + 4921344);
  float* rel  = (float*)(ws + 4970496);
  float* tpp  = (float*)(ws + 4970752);
  float* outp = (float*)d_out;

  prep_w   <<<144, 256, 0, stream>>>(Wq, Wo, Wg1, WqI, WoI, WaI, WbI);
  prep_kv  <<<8,   768, 0, stream>>>(ce, Wk, bk, Wv, bv, Kc, VT);
  prep_misc<<<6,   256, 0, stream>>>(Wg1, ce, wg1c, cp);
  pool1    <<<512, 256, 0, stream>>>(hs, tpp);
  pool2    <<<48,  256, 0, stream>>>(tpp, tp);
  pool3    <<<16,  256, 0, stream>>>(tp, cp, rel);
  hipFuncSetAttribute(reinterpret_cast<const void*>(ka),
                      hipFuncAttributeMaxDynamicSharedMemorySize, 147456);
  hipFuncSetAttribute(reinterpret_cast<const void*>(kb),
                      hipFuncAttributeMaxDynamicSharedMemorySize, 66048);
  ka<<<512, 512, 147456, stream>>>(hs, WqI, WoI, Kc, VT, bq, bo, outp);
  kb<<<512, 512, 66048,  stream>>>(hs, WaI, WbI, bg1, wg1c, Wg2, bg2, rel, lng, lnb, outp);
}